// Round 1
// baseline (1584.102 us; speedup 1.0000x reference)
//
#include <hip/hip_runtime.h>
#include <math.h>

// MACE-like block, f32 baseline.
// N=10000 nodes, E=160000 edges, C=64 channels, 16 sph (lmax=3), S=10 species.
//
// ws layout (floats):
//   agg0 [N*16*64]   scatter target, interaction 1   (layout n,m,c)
//   agg1 [N*16*64]   scatter target, interaction 2
//   up0  [N*64]      lu0-transformed node feats (m=0)
//   up1  [N*4*64]    lu1-transformed f1 (layout n,m,c)
//   res  [N*64]
//   pack1[64*64*4]   rw2[0] cols {0,1,2,3}       per (h,c), float4
//   pack2[64*64*8]   rw2[1] cols {0,1,2,3,5,9,-,-} per (h,c), stride 8

__device__ __forceinline__ float silu_f(float x) { return x / (1.0f + expf(-x)); }

__device__ __forceinline__ float reduce64(float v) {
#pragma unroll
  for (int off = 32; off > 0; off >>= 1) v += __shfl_xor(v, off, 64);
  return v;
}

__device__ __forceinline__ void compute_Y(float x, float y, float z, float* Y) {
  float x2 = x * x, y2 = y * y, z2 = z * z;
  Y[0] = 1.0f;
  Y[1] = 1.7320508f * x;
  Y[2] = 1.7320508f * y;
  Y[3] = 1.7320508f * z;
  Y[4] = 3.8729833f * x * y;
  Y[5] = 3.8729833f * y * z;
  Y[6] = 1.118034f * (3.0f * z2 - 1.0f);
  Y[7] = 3.8729833f * x * z;
  Y[8] = 1.9364917f * (x2 - y2);
  Y[9] = 2.09165f * y * (3.0f * x2 - y2);
  Y[10] = 10.246951f * x * y * z;
  Y[11] = 1.6201852f * y * (5.0f * z2 - 1.0f);
  Y[12] = 1.3228757f * z * (5.0f * z2 - 3.0f);
  Y[13] = 1.6201852f * x * (5.0f * z2 - 1.0f);
  Y[14] = 5.1234753f * z * (x2 - y2);
  Y[15] = 2.09165f * x * (x2 - 3.0f * y2);
}

__device__ __forceinline__ void compute_rb(float r, float inv_r, float* rb) {
  // bess_n = sqrt(2/5) * sin(n*pi*r/5)/(r+1e-8), n=1..8 ; polynomial envelope p=5
  float t = fminf(r * 0.2f, 1.0f);
  float t2 = t * t;
  float t5 = t2 * t2 * t;
  float env = 1.0f + t5 * (-21.0f + t * (35.0f - 15.0f * t));
  float th = 0.62831853f * r;  // pi*r/5
  float s1 = sinf(th), c1 = cosf(th);
  float c2 = 2.0f * c1;
  float sprev = 0.0f, scur = s1;
  float coef = 0.63245553f * inv_r * env;
#pragma unroll
  for (int k = 0; k < 8; k++) {
    rb[k] = coef * scur;
    float snxt = c2 * scur - sprev;
    sprev = scur; scur = snxt;
  }
}

__device__ __forceinline__ int l_of_m(int m) {
  return (m == 0) ? 0 : ((m < 4) ? 1 : ((m < 9) ? 2 : 3));
}

// ---------------------------------------------------------------- pack rw2
__global__ __launch_bounds__(256) void k_pack(const float* __restrict__ rw2,
                                              float* __restrict__ pack1,
                                              float* __restrict__ pack2) {
  int idx = blockIdx.x * 256 + threadIdx.x;  // over h*64+c, 4096 total
  if (idx >= 4096) return;
  int h = idx >> 6, c = idx & 63;
  const float* s0 = rw2 + h * 768 + c * 12;           // interaction 1
  const float* s1 = rw2 + 49152 + h * 768 + c * 12;   // interaction 2
  float* d1 = pack1 + idx * 4;
  d1[0] = s0[0]; d1[1] = s0[1]; d1[2] = s0[2]; d1[3] = s0[3];
  float* d2 = pack2 + idx * 8;
  d2[0] = s1[0]; d2[1] = s1[1]; d2[2] = s1[2]; d2[3] = s1[3];
  d2[4] = s1[5];  // R1[:, :, 1]
  d2[5] = s1[9];  // R2[:, :, 1]
  d2[6] = 0.0f; d2[7] = 0.0f;
}

// ---------------------------------------------------------------- up0
__global__ __launch_bounds__(256) void k_up0(const float* __restrict__ embed,
                                             const float* __restrict__ lu0,
                                             const int* __restrict__ species,
                                             float* __restrict__ up0, int N) {
  int wave = threadIdx.x >> 6, lane = threadIdx.x & 63;
  int n = (blockIdx.x << 2) + wave;
  if (n >= N) return;
  int sp = species[n];
  const float* er = embed + sp * 64;
  float acc = 0.0f;
#pragma unroll 8
  for (int c = 0; c < 64; c++) acc += er[c] * lu0[c * 64 + lane];
  up0[(size_t)n * 64 + lane] = acc;
}

// ---------------------------------------------------------------- edge kernel 1
__global__ __launch_bounds__(256) void k_edge1(const float* __restrict__ ev,
                                               const float* __restrict__ rw1,
                                               const float* __restrict__ pack1,
                                               const float* __restrict__ up0,
                                               const int* __restrict__ senders,
                                               const int* __restrict__ receivers,
                                               float* __restrict__ agg0, int E) {
  int wave = threadIdx.x >> 6, lane = threadIdx.x & 63;
  int e = (blockIdx.x << 2) + wave;
  bool ok = (e < E);
  int ee = ok ? e : 0;
  __shared__ float hsh[4][64];

  float vx = ev[ee * 3 + 0], vy = ev[ee * 3 + 1], vz = ev[ee * 3 + 2];
  float r = sqrtf(vx * vx + vy * vy + vz * vz);
  float inv_r = 1.0f / (r + 1e-8f);
  float x = vx * inv_r, y = vy * inv_r, z = vz * inv_r;
  float Y[16]; compute_Y(x, y, z, Y);
  float rb[8]; compute_rb(r, inv_r, rb);

  // hidden unit `lane`
  float acc = 0.0f;
#pragma unroll
  for (int k = 0; k < 8; k++) acc += rb[k] * rw1[k * 64 + lane];
  hsh[wave][lane] = silu_f(acc);
  __syncthreads();

  // R0[lane][0..3] = hidden . rw2cols
  float4 R = {0.f, 0.f, 0.f, 0.f};
  const float4* pk = (const float4*)pack1;
#pragma unroll 8
  for (int h = 0; h < 64; h++) {
    float hv = hsh[wave][h];
    float4 w = pk[(h << 6) + lane];
    R.x += hv * w.x; R.y += hv * w.y; R.z += hv * w.z; R.w += hv * w.w;
  }

  int s = senders[ee], rc = receivers[ee];
  float hs0 = up0[(size_t)s * 64 + lane];
  float p0 = R.x * hs0, p1 = R.y * hs0, p2 = R.z * hs0, p3 = R.w * hs0;
  if (ok) {
    float* base = agg0 + ((size_t)rc << 10) + lane;  // (n, m, c)
#pragma unroll
    for (int m = 0; m < 16; m++) {
      float pm = (m == 0) ? p0 : ((m < 4) ? p1 : ((m < 9) ? p2 : p3));
      atomicAdd(base + (m << 6), pm * Y[m]);
    }
  }
}

// ---------------------------------------------------------------- edge kernel 2
__global__ __launch_bounds__(256) void k_edge2(const float* __restrict__ ev,
                                               const float* __restrict__ rw1b,
                                               const float* __restrict__ pack2,
                                               const float* __restrict__ up1,
                                               const int* __restrict__ senders,
                                               const int* __restrict__ receivers,
                                               float* __restrict__ agg1, int E) {
  int wave = threadIdx.x >> 6, lane = threadIdx.x & 63;
  int e = (blockIdx.x << 2) + wave;
  bool ok = (e < E);
  int ee = ok ? e : 0;
  __shared__ float hsh[4][64];

  float vx = ev[ee * 3 + 0], vy = ev[ee * 3 + 1], vz = ev[ee * 3 + 2];
  float r = sqrtf(vx * vx + vy * vy + vz * vz);
  float inv_r = 1.0f / (r + 1e-8f);
  float x = vx * inv_r, y = vy * inv_r, z = vz * inv_r;
  float Y[16]; compute_Y(x, y, z, Y);
  float rb[8]; compute_rb(r, inv_r, rb);

  float acc = 0.0f;
#pragma unroll
  for (int k = 0; k < 8; k++) acc += rb[k] * rw1b[k * 64 + lane];
  hsh[wave][lane] = silu_f(acc);
  __syncthreads();

  // cols {0,1,2,3} -> R0, col4 -> R1[:,1], col5 -> R2[:,1]
  float4 R = {0.f, 0.f, 0.f, 0.f};
  float c5 = 0.0f, c9 = 0.0f;
#pragma unroll 8
  for (int h = 0; h < 64; h++) {
    float hv = hsh[wave][h];
    const float* p2 = pack2 + ((size_t)((h << 6) + lane) << 3);
    float4 w = *(const float4*)p2;
    float2 w2 = *(const float2*)(p2 + 4);
    R.x += hv * w.x; R.y += hv * w.y; R.z += hv * w.z; R.w += hv * w.w;
    c5 += hv * w2.x; c9 += hv * w2.y;
  }

  int s = senders[ee], rc = receivers[ee];
  const float* hsv = up1 + ((size_t)s << 8) + lane;  // (n, m, c)
  float hs0 = hsv[0], hs1 = hsv[64], hs2 = hsv[128], hs3 = hsv[192];
  float q0 = R.x * hs0, q1 = R.y * hs0, q2 = R.z * hs0, q3 = R.w * hs0;

  if (ok) {
    float* base = agg1 + ((size_t)rc << 10) + lane;
    float sumY = hs1 * Y[1] + hs2 * Y[2] + hs3 * Y[3];
    atomicAdd(base, q0 + c9 * sumY);                    // m=0 (Y0 = 1)
    atomicAdd(base + 64,  q1 * Y[1] + c5 * hs1);        // m=1..3 (Y0=1 factor)
    atomicAdd(base + 128, q1 * Y[2] + c5 * hs2);
    atomicAdd(base + 192, q1 * Y[3] + c5 * hs3);
#pragma unroll
    for (int m = 4; m < 9; m++)  atomicAdd(base + (m << 6), q2 * Y[m]);
#pragma unroll
    for (int m = 9; m < 16; m++) atomicAdd(base + (m << 6), q3 * Y[m]);
  }
}

// ---------------------------------------------------------------- node kernel 1
__global__ __launch_bounds__(64) void k_node1(const float* __restrict__ agg0,
                                              const float* __restrict__ ld0,
                                              const float* __restrict__ sel_w,
                                              const float* __restrict__ pw0,
                                              const float* __restrict__ res_w,
                                              const float* __restrict__ lu1,
                                              const float* __restrict__ read0,
                                              const int* __restrict__ species,
                                              float* __restrict__ out,
                                              float* __restrict__ res,
                                              float* __restrict__ up1, int N) {
  int n = blockIdx.x, d = threadIdx.x;
  int sp = species[n];
  __shared__ float sA[1024], sB[1024];

  const float* ag = agg0 + ((size_t)n << 10);
#pragma unroll
  for (int m = 0; m < 16; m++) sA[m * 64 + d] = ag[m * 64 + d] * 0.0625f;
  __syncthreads();

  // fint[d][m] = sum_c agg[m][c] * ld0[l(m)][c][d]
  float fr[16];
  for (int m = 0; m < 16; m++) {
    const float* W = ld0 + l_of_m(m) * 4096 + d;
    float a = 0.0f;
#pragma unroll 16
    for (int c = 0; c < 64; c++) a += sA[m * 64 + c] * W[c * 64];
    fr[m] = a;
  }
#pragma unroll
  for (int m = 0; m < 16; m++) sB[m * 64 + d] = fr[m];
  __syncthreads();  // sA free after this (all lanes read sA before writing sB)

  // f[d][m] = sum_c fint[c][m] * sel_w[sp][l(m)][c][d]
  float f2r[16];
  for (int m = 0; m < 16; m++) {
    const float* W = sel_w + ((size_t)(sp * 4 + l_of_m(m)) << 12) + d;
    float a = 0.0f;
#pragma unroll 16
    for (int c = 0; c < 64; c++) a += sB[m * 64 + c] * W[c * 64];
    f2r[m] = a;
  }
  float s0 = f2r[0];
  float t = 1.0f + s0 + s0 * s0;
#pragma unroll
  for (int m = 0; m < 4; m++) sA[m * 64 + d] = f2r[m] * t;
  __syncthreads();  // sB free after this

  // f1[d][m] = sum_c tf[c][m] * prod_w0[sp][c][d], m<4
  float f1r[4];
  for (int m = 0; m < 4; m++) {
    const float* W = pw0 + ((size_t)sp << 12) + d;
    float a = 0.0f;
#pragma unroll 16
    for (int c = 0; c < 64; c++) a += sA[m * 64 + c] * W[c * 64];
    f1r[m] = a;
  }
#pragma unroll
  for (int m = 0; m < 4; m++) sB[m * 64 + d] = f1r[m];
  __syncthreads();

  // out0 = f1[:,0] . read0
  float v = reduce64(f1r[0] * read0[d]);
  if (d == 0) out[2 * n] = v;

  // res[d] = sum_c f1[c][0] * res_w[sp][c][d]
  {
    const float* W = res_w + ((size_t)sp << 12) + d;
    float a = 0.0f;
#pragma unroll 16
    for (int c = 0; c < 64; c++) a += sB[c] * W[c * 64];
    res[(size_t)n * 64 + d] = a;
  }
  // up1[n][0][d] = sum_c f1[c][0] * lu1[0][c][d]
  {
    float a = 0.0f;
#pragma unroll 16
    for (int c = 0; c < 64; c++) a += sB[c] * lu1[c * 64 + d];
    up1[((size_t)n << 8) + d] = a;
  }
  // up1[n][m][d] = sum_c f1[c][m] * lu1[1][c][d], m=1..3
  for (int m = 1; m < 4; m++) {
    float a = 0.0f;
#pragma unroll 16
    for (int c = 0; c < 64; c++) a += sB[m * 64 + c] * lu1[4096 + c * 64 + d];
    up1[((size_t)n << 8) + (m << 6) + d] = a;
  }
}

// ---------------------------------------------------------------- node kernel 2
__global__ __launch_bounds__(64) void k_node2(const float* __restrict__ agg1,
                                              const float* __restrict__ ld1,
                                              const float* __restrict__ pw1,
                                              const float* __restrict__ res,
                                              const float* __restrict__ mlp_w1,
                                              const float* __restrict__ mlp_w2,
                                              const int* __restrict__ species,
                                              float* __restrict__ out, int N) {
  int n = blockIdx.x, d = threadIdx.x;
  int sp = species[n];
  __shared__ float sA[1024];

  const float* ag = agg1 + ((size_t)n << 10);
#pragma unroll
  for (int m = 0; m < 16; m++) sA[m * 64 + d] = ag[m * 64 + d] * 0.0625f;
  __syncthreads();

  // g[d][m] = sum_c agg[m][c] * ld1[l(m)][c][d]
  float g[16];
  for (int m = 0; m < 16; m++) {
    const float* W = ld1 + l_of_m(m) * 4096 + d;
    float a = 0.0f;
#pragma unroll 16
    for (int c = 0; c < 64; c++) a += sA[m * 64 + c] * W[c * 64];
    g[m] = a;
  }
  float inv = g[0];
#pragma unroll
  for (int m = 1; m < 16; m++) inv += g[m] * g[m];
  float q = inv + inv * inv;
  __syncthreads();
  sA[d] = q;
  __syncthreads();

  // f2[d] = sum_c q[c] * prod_w1[sp][c][d] + res[n][d]
  float a = res[(size_t)n * 64 + d];
  {
    const float* W = pw1 + ((size_t)sp << 12) + d;
#pragma unroll 16
    for (int c = 0; c < 64; c++) a += sA[c] * W[c * 64];
  }
  sA[64 + d] = a;
  __syncthreads();

  float val = 0.0f;
  if (d < 32) {
    float h = 0.0f;
#pragma unroll 16
    for (int c = 0; c < 64; c++) h += sA[64 + c] * mlp_w1[c * 32 + d];
    val = silu_f(h) * mlp_w2[d];
  }
  val = reduce64(val);
  if (d == 0) out[2 * n + 1] = val;
}

// ---------------------------------------------------------------- launch
extern "C" void kernel_launch(void* const* d_in, const int* in_sizes, int n_in,
                              void* d_out, int out_size, void* d_ws, size_t ws_size,
                              hipStream_t stream) {
  const float* ev      = (const float*)d_in[0];
  const float* embed   = (const float*)d_in[1];
  const float* rw1     = (const float*)d_in[2];
  const float* rw2     = (const float*)d_in[3];
  const float* lu0     = (const float*)d_in[4];
  const float* lu1     = (const float*)d_in[5];
  const float* ld      = (const float*)d_in[6];
  const float* sel_w   = (const float*)d_in[7];
  const float* pw0     = (const float*)d_in[8];
  const float* pw1     = (const float*)d_in[9];
  const float* res_w   = (const float*)d_in[10];
  const float* read0   = (const float*)d_in[11];
  const float* mlp_w1  = (const float*)d_in[12];
  const float* mlp_w2  = (const float*)d_in[13];
  const int* species   = (const int*)d_in[14];
  const int* senders   = (const int*)d_in[15];
  const int* receivers = (const int*)d_in[16];
  float* out = (float*)d_out;

  int N = in_sizes[14];
  int E = in_sizes[15];

  float* ws = (float*)d_ws;
  size_t o = 0;
  float* agg0 = ws + o;  o += (size_t)N * 1024;
  float* agg1 = ws + o;  o += (size_t)N * 1024;
  float* up0  = ws + o;  o += (size_t)N * 64;
  float* up1  = ws + o;  o += (size_t)N * 256;
  float* resb = ws + o;  o += (size_t)N * 64;
  float* pack1 = ws + o; o += 16384;
  float* pack2 = ws + o; o += 32768;

  // zero the two scatter targets (contiguous)
  hipMemsetAsync(agg0, 0, (size_t)N * 2048 * sizeof(float), stream);

  k_pack<<<16, 256, 0, stream>>>(rw2, pack1, pack2);
  k_up0<<<(N + 3) / 4, 256, 0, stream>>>(embed, lu0, species, up0, N);
  k_edge1<<<(E + 3) / 4, 256, 0, stream>>>(ev, rw1, pack1, up0, senders, receivers, agg0, E);
  k_node1<<<N, 64, 0, stream>>>(agg0, ld, sel_w, pw0, res_w, lu1, read0, species,
                                out, resb, up1, N);
  k_edge2<<<(E + 3) / 4, 256, 0, stream>>>(ev, rw1 + 512, pack2, up1, senders, receivers, agg1, E);
  k_node2<<<N, 64, 0, stream>>>(agg1, ld + 16384, pw1, resb, mlp_w1, mlp_w2, species, out, N);
}

// Round 2
// 1413.207 us; speedup vs baseline: 1.1209x; 1.1209x over previous
//
#include <hip/hip_runtime.h>
#include <math.h>

// MACE-like block, f32, CSR-sorted edge aggregation (atomics only on run change).
// N=10000 nodes, E=160000 edges, C=64 channels, 16 sph (lmax=3), S=10 species.

#define CHUNK 32

__device__ __forceinline__ float silu_f(float x) { return x / (1.0f + expf(-x)); }

__device__ __forceinline__ float reduce64(float v) {
#pragma unroll
  for (int off = 32; off > 0; off >>= 1) v += __shfl_xor(v, off, 64);
  return v;
}

__device__ __forceinline__ void compute_Y(float x, float y, float z, float* Y) {
  float x2 = x * x, y2 = y * y, z2 = z * z;
  Y[0] = 1.0f;
  Y[1] = 1.7320508f * x;
  Y[2] = 1.7320508f * y;
  Y[3] = 1.7320508f * z;
  Y[4] = 3.8729833f * x * y;
  Y[5] = 3.8729833f * y * z;
  Y[6] = 1.118034f * (3.0f * z2 - 1.0f);
  Y[7] = 3.8729833f * x * z;
  Y[8] = 1.9364917f * (x2 - y2);
  Y[9] = 2.09165f * y * (3.0f * x2 - y2);
  Y[10] = 10.246951f * x * y * z;
  Y[11] = 1.6201852f * y * (5.0f * z2 - 1.0f);
  Y[12] = 1.3228757f * z * (5.0f * z2 - 3.0f);
  Y[13] = 1.6201852f * x * (5.0f * z2 - 1.0f);
  Y[14] = 5.1234753f * z * (x2 - y2);
  Y[15] = 2.09165f * x * (x2 - 3.0f * y2);
}

__device__ __forceinline__ void compute_rb(float r, float inv_r, float* rb) {
  float t = fminf(r * 0.2f, 1.0f);
  float t2 = t * t;
  float t5 = t2 * t2 * t;
  float env = 1.0f + t5 * (-21.0f + t * (35.0f - 15.0f * t));
  float th = 0.62831853f * r;  // pi*r/5
  float s1 = sinf(th), c1 = cosf(th);
  float c2 = 2.0f * c1;
  float sprev = 0.0f, scur = s1;
  float coef = 0.63245553f * inv_r * env;
#pragma unroll
  for (int k = 0; k < 8; k++) {
    rb[k] = coef * scur;
    float snxt = c2 * scur - sprev;
    sprev = scur; scur = snxt;
  }
}

__device__ __forceinline__ int l_of_m(int m) {
  return (m == 0) ? 0 : ((m < 4) ? 1 : ((m < 9) ? 2 : 3));
}

// ---------------------------------------------------------------- CSR build
__global__ __launch_bounds__(256) void k_hist(const int* __restrict__ receivers,
                                              int* __restrict__ cnt, int E) {
  int e = blockIdx.x * 256 + threadIdx.x;
  if (e < E) atomicAdd(&cnt[receivers[e]], 1);
}

// single block, 256 threads; deg aliases cursor (read deg[i] before overwrite)
__global__ __launch_bounds__(256) void k_scan(const int* __restrict__ deg,
                                              int* __restrict__ row_start,
                                              int* __restrict__ cursor, int N) {
  __shared__ int part[256];
  int t = threadIdx.x;
  int K = (N + 255) / 256;
  int lo = t * K, hi = min(lo + K, N);
  int s = 0;
  for (int i = lo; i < hi; i++) s += deg[i];
  part[t] = s;
  __syncthreads();
  for (int d = 1; d < 256; d <<= 1) {
    int v = (t >= d) ? part[t - d] : 0;
    __syncthreads();
    part[t] += v;
    __syncthreads();
  }
  int run = (t == 0) ? 0 : part[t - 1];
  for (int i = lo; i < hi; i++) {
    int di = deg[i];            // read before overwrite (deg aliases cursor)
    row_start[i] = run;
    cursor[i] = run;
    run += di;
  }
  if (t == 255) row_start[N] = part[255];
}

__global__ __launch_bounds__(256) void k_scatter(const int* __restrict__ receivers,
                                                 int* __restrict__ cursor,
                                                 int* __restrict__ perm,
                                                 int* __restrict__ rsort, int E) {
  int e = blockIdx.x * 256 + threadIdx.x;
  if (e < E) {
    int r = receivers[e];
    int pos = atomicAdd(&cursor[r], 1);
    perm[pos] = e;
    rsort[pos] = r;
  }
}

// ---------------------------------------------------------------- pack rw2
__global__ __launch_bounds__(256) void k_pack(const float* __restrict__ rw2,
                                              float* __restrict__ pack1,
                                              float* __restrict__ pack2) {
  int idx = blockIdx.x * 256 + threadIdx.x;  // over h*64+c, 4096 total
  if (idx >= 4096) return;
  int h = idx >> 6, c = idx & 63;
  const float* s0 = rw2 + h * 768 + c * 12;
  const float* s1 = rw2 + 49152 + h * 768 + c * 12;
  float* d1 = pack1 + idx * 4;
  d1[0] = s0[0]; d1[1] = s0[1]; d1[2] = s0[2]; d1[3] = s0[3];
  float* d2 = pack2 + idx * 8;
  d2[0] = s1[0]; d2[1] = s1[1]; d2[2] = s1[2]; d2[3] = s1[3];
  d2[4] = s1[5];  // R1[:, :, 1]
  d2[5] = s1[9];  // R2[:, :, 1]
  d2[6] = 0.0f; d2[7] = 0.0f;
}

// ---------------------------------------------------------------- up0
__global__ __launch_bounds__(256) void k_up0(const float* __restrict__ embed,
                                             const float* __restrict__ lu0,
                                             const int* __restrict__ species,
                                             float* __restrict__ up0, int N) {
  int wave = threadIdx.x >> 6, lane = threadIdx.x & 63;
  int n = (blockIdx.x << 2) + wave;
  if (n >= N) return;
  int sp = species[n];
  const float* er = embed + sp * 64;
  float acc = 0.0f;
#pragma unroll 8
  for (int c = 0; c < 64; c++) acc += er[c] * lu0[c * 64 + lane];
  up0[(size_t)n * 64 + lane] = acc;
}

// ---------------------------------------------------------------- edge kernel 1
// wave processes CHUNK consecutive receiver-sorted edges, accumulating in regs,
// flushing to agg0 via atomicAdd only when the receiver changes.
__global__ __launch_bounds__(256) void k_edge1(const float* __restrict__ ev,
                                               const float* __restrict__ rw1,
                                               const float* __restrict__ pack1,
                                               const float* __restrict__ up0,
                                               const int* __restrict__ senders,
                                               const int* __restrict__ perm,
                                               const int* __restrict__ rsort,
                                               float* __restrict__ agg0, int E) {
  int wave = threadIdx.x >> 6, lane = threadIdx.x & 63;
  int j0 = (blockIdx.x * 4 + wave) * CHUNK;
  __shared__ float hsh[4][64];

  float acc[16];
#pragma unroll
  for (int m = 0; m < 16; m++) acc[m] = 0.0f;
  int cur_r = (j0 < E) ? rsort[j0] : -1;

  for (int t = 0; t < CHUNK; t++) {
    int j = j0 + t;
    bool ok = (j < E);
    int e = ok ? perm[j] : 0;

    float vx = ev[e * 3 + 0], vy = ev[e * 3 + 1], vz = ev[e * 3 + 2];
    float r = sqrtf(vx * vx + vy * vy + vz * vz);
    float inv_r = 1.0f / (r + 1e-8f);
    float Y[16]; compute_Y(vx * inv_r, vy * inv_r, vz * inv_r, Y);
    float rb[8]; compute_rb(r, inv_r, rb);

    float h = 0.0f;
#pragma unroll
    for (int k = 0; k < 8; k++) h += rb[k] * rw1[k * 64 + lane];
    __syncthreads();           // protect WAR on hsh across loop iterations
    hsh[wave][lane] = silu_f(h);
    __syncthreads();

    float4 R = {0.f, 0.f, 0.f, 0.f};
    const float4* pk = (const float4*)pack1;
#pragma unroll 8
    for (int hh = 0; hh < 64; hh++) {
      float hv = hsh[wave][hh];
      float4 w = pk[(hh << 6) + lane];
      R.x += hv * w.x; R.y += hv * w.y; R.z += hv * w.z; R.w += hv * w.w;
    }

    int s = senders[e];
    float hs0 = up0[(size_t)s * 64 + lane];
    float p0 = R.x * hs0, p1 = R.y * hs0, p2 = R.z * hs0, p3 = R.w * hs0;

    int rr = ok ? rsort[j] : -2;
    if (rr != cur_r) {         // wave-uniform
      if (cur_r >= 0) {
        float* base = agg0 + ((size_t)cur_r << 10) + lane;
#pragma unroll
        for (int m = 0; m < 16; m++) {
          if (acc[m] != 0.0f || true) atomicAdd(base + (m << 6), acc[m]);
        }
      }
#pragma unroll
      for (int m = 0; m < 16; m++) acc[m] = 0.0f;
      cur_r = rr;
    }
    if (ok) {
#pragma unroll
      for (int m = 0; m < 16; m++) {
        float pm = (m == 0) ? p0 : ((m < 4) ? p1 : ((m < 9) ? p2 : p3));
        acc[m] += pm * Y[m];
      }
    }
  }
  if (cur_r >= 0) {
    float* base = agg0 + ((size_t)cur_r << 10) + lane;
#pragma unroll
    for (int m = 0; m < 16; m++) atomicAdd(base + (m << 6), acc[m]);
  }
}

// ---------------------------------------------------------------- edge kernel 2
__global__ __launch_bounds__(256) void k_edge2(const float* __restrict__ ev,
                                               const float* __restrict__ rw1b,
                                               const float* __restrict__ pack2,
                                               const float* __restrict__ up1,
                                               const int* __restrict__ senders,
                                               const int* __restrict__ perm,
                                               const int* __restrict__ rsort,
                                               float* __restrict__ agg1, int E) {
  int wave = threadIdx.x >> 6, lane = threadIdx.x & 63;
  int j0 = (blockIdx.x * 4 + wave) * CHUNK;
  __shared__ float hsh[4][64];

  float acc[16];
#pragma unroll
  for (int m = 0; m < 16; m++) acc[m] = 0.0f;
  int cur_r = (j0 < E) ? rsort[j0] : -1;

  for (int t = 0; t < CHUNK; t++) {
    int j = j0 + t;
    bool ok = (j < E);
    int e = ok ? perm[j] : 0;

    float vx = ev[e * 3 + 0], vy = ev[e * 3 + 1], vz = ev[e * 3 + 2];
    float r = sqrtf(vx * vx + vy * vy + vz * vz);
    float inv_r = 1.0f / (r + 1e-8f);
    float Y[16]; compute_Y(vx * inv_r, vy * inv_r, vz * inv_r, Y);
    float rb[8]; compute_rb(r, inv_r, rb);

    float h = 0.0f;
#pragma unroll
    for (int k = 0; k < 8; k++) h += rb[k] * rw1b[k * 64 + lane];
    __syncthreads();
    hsh[wave][lane] = silu_f(h);
    __syncthreads();

    float4 R = {0.f, 0.f, 0.f, 0.f};
    float c5 = 0.0f, c9 = 0.0f;
#pragma unroll 8
    for (int hh = 0; hh < 64; hh++) {
      float hv = hsh[wave][hh];
      const float* p2 = pack2 + ((size_t)((hh << 6) + lane) << 3);
      float4 w = *(const float4*)p2;
      float2 w2 = *(const float2*)(p2 + 4);
      R.x += hv * w.x; R.y += hv * w.y; R.z += hv * w.z; R.w += hv * w.w;
      c5 += hv * w2.x; c9 += hv * w2.y;
    }

    int s = senders[e];
    const float* hsv = up1 + ((size_t)s << 8) + lane;  // (n, m, c)
    float hs0 = hsv[0], hs1 = hsv[64], hs2 = hsv[128], hs3 = hsv[192];
    float q0 = R.x * hs0, q1 = R.y * hs0, q2 = R.z * hs0, q3 = R.w * hs0;

    int rr = ok ? rsort[j] : -2;
    if (rr != cur_r) {
      if (cur_r >= 0) {
        float* base = agg1 + ((size_t)cur_r << 10) + lane;
#pragma unroll
        for (int m = 0; m < 16; m++) atomicAdd(base + (m << 6), acc[m]);
      }
#pragma unroll
      for (int m = 0; m < 16; m++) acc[m] = 0.0f;
      cur_r = rr;
    }
    if (ok) {
      float sumY = hs1 * Y[1] + hs2 * Y[2] + hs3 * Y[3];
      acc[0] += q0 + c9 * sumY;
      acc[1] += q1 * Y[1] + c5 * hs1;
      acc[2] += q1 * Y[2] + c5 * hs2;
      acc[3] += q1 * Y[3] + c5 * hs3;
#pragma unroll
      for (int m = 4; m < 9; m++)  acc[m] += q2 * Y[m];
#pragma unroll
      for (int m = 9; m < 16; m++) acc[m] += q3 * Y[m];
    }
  }
  if (cur_r >= 0) {
    float* base = agg1 + ((size_t)cur_r << 10) + lane;
#pragma unroll
    for (int m = 0; m < 16; m++) atomicAdd(base + (m << 6), acc[m]);
  }
}

// ---------------------------------------------------------------- node kernel 1
__global__ __launch_bounds__(64) void k_node1(const float* __restrict__ agg0,
                                              const float* __restrict__ ld0,
                                              const float* __restrict__ sel_w,
                                              const float* __restrict__ pw0,
                                              const float* __restrict__ res_w,
                                              const float* __restrict__ lu1,
                                              const float* __restrict__ read0,
                                              const int* __restrict__ species,
                                              float* __restrict__ out,
                                              float* __restrict__ res,
                                              float* __restrict__ up1, int N) {
  int n = blockIdx.x, d = threadIdx.x;
  int sp = species[n];
  __shared__ float sA[1024], sB[1024];

  const float* ag = agg0 + ((size_t)n << 10);
#pragma unroll
  for (int m = 0; m < 16; m++) sA[m * 64 + d] = ag[m * 64 + d] * 0.0625f;
  __syncthreads();

  float fr[16];
  for (int m = 0; m < 16; m++) {
    const float* W = ld0 + l_of_m(m) * 4096 + d;
    float a = 0.0f;
#pragma unroll 16
    for (int c = 0; c < 64; c++) a += sA[m * 64 + c] * W[c * 64];
    fr[m] = a;
  }
#pragma unroll
  for (int m = 0; m < 16; m++) sB[m * 64 + d] = fr[m];
  __syncthreads();

  float f2r[16];
  for (int m = 0; m < 16; m++) {
    const float* W = sel_w + ((size_t)(sp * 4 + l_of_m(m)) << 12) + d;
    float a = 0.0f;
#pragma unroll 16
    for (int c = 0; c < 64; c++) a += sB[m * 64 + c] * W[c * 64];
    f2r[m] = a;
  }
  float s0 = f2r[0];
  float tt = 1.0f + s0 + s0 * s0;
#pragma unroll
  for (int m = 0; m < 4; m++) sA[m * 64 + d] = f2r[m] * tt;
  __syncthreads();

  float f1r[4];
  for (int m = 0; m < 4; m++) {
    const float* W = pw0 + ((size_t)sp << 12) + d;
    float a = 0.0f;
#pragma unroll 16
    for (int c = 0; c < 64; c++) a += sA[m * 64 + c] * W[c * 64];
    f1r[m] = a;
  }
#pragma unroll
  for (int m = 0; m < 4; m++) sB[m * 64 + d] = f1r[m];
  __syncthreads();

  float v = reduce64(f1r[0] * read0[d]);
  if (d == 0) out[2 * n] = v;

  {
    const float* W = res_w + ((size_t)sp << 12) + d;
    float a = 0.0f;
#pragma unroll 16
    for (int c = 0; c < 64; c++) a += sB[c] * W[c * 64];
    res[(size_t)n * 64 + d] = a;
  }
  {
    float a = 0.0f;
#pragma unroll 16
    for (int c = 0; c < 64; c++) a += sB[c] * lu1[c * 64 + d];
    up1[((size_t)n << 8) + d] = a;
  }
  for (int m = 1; m < 4; m++) {
    float a = 0.0f;
#pragma unroll 16
    for (int c = 0; c < 64; c++) a += sB[m * 64 + c] * lu1[4096 + c * 64 + d];
    up1[((size_t)n << 8) + (m << 6) + d] = a;
  }
}

// ---------------------------------------------------------------- node kernel 2
__global__ __launch_bounds__(64) void k_node2(const float* __restrict__ agg1,
                                              const float* __restrict__ ld1,
                                              const float* __restrict__ pw1,
                                              const float* __restrict__ res,
                                              const float* __restrict__ mlp_w1,
                                              const float* __restrict__ mlp_w2,
                                              const int* __restrict__ species,
                                              float* __restrict__ out, int N) {
  int n = blockIdx.x, d = threadIdx.x;
  int sp = species[n];
  __shared__ float sA[1024];

  const float* ag = agg1 + ((size_t)n << 10);
#pragma unroll
  for (int m = 0; m < 16; m++) sA[m * 64 + d] = ag[m * 64 + d] * 0.0625f;
  __syncthreads();

  float g[16];
  for (int m = 0; m < 16; m++) {
    const float* W = ld1 + l_of_m(m) * 4096 + d;
    float a = 0.0f;
#pragma unroll 16
    for (int c = 0; c < 64; c++) a += sA[m * 64 + c] * W[c * 64];
    g[m] = a;
  }
  float inv = g[0];
#pragma unroll
  for (int m = 1; m < 16; m++) inv += g[m] * g[m];
  float q = inv + inv * inv;
  __syncthreads();
  sA[d] = q;
  __syncthreads();

  float a = res[(size_t)n * 64 + d];
  {
    const float* W = pw1 + ((size_t)sp << 12) + d;
#pragma unroll 16
    for (int c = 0; c < 64; c++) a += sA[c] * W[c * 64];
  }
  sA[64 + d] = a;
  __syncthreads();

  float val = 0.0f;
  if (d < 32) {
    float h = 0.0f;
#pragma unroll 16
    for (int c = 0; c < 64; c++) h += sA[64 + c] * mlp_w1[c * 32 + d];
    val = silu_f(h) * mlp_w2[d];
  }
  val = reduce64(val);
  if (d == 0) out[2 * n + 1] = val;
}

// ---------------------------------------------------------------- launch
extern "C" void kernel_launch(void* const* d_in, const int* in_sizes, int n_in,
                              void* d_out, int out_size, void* d_ws, size_t ws_size,
                              hipStream_t stream) {
  const float* ev      = (const float*)d_in[0];
  const float* embed   = (const float*)d_in[1];
  const float* rw1     = (const float*)d_in[2];
  const float* rw2     = (const float*)d_in[3];
  const float* lu0     = (const float*)d_in[4];
  const float* lu1     = (const float*)d_in[5];
  const float* ld      = (const float*)d_in[6];
  const float* sel_w   = (const float*)d_in[7];
  const float* pw0     = (const float*)d_in[8];
  const float* pw1     = (const float*)d_in[9];
  const float* res_w   = (const float*)d_in[10];
  const float* read0   = (const float*)d_in[11];
  const float* mlp_w1  = (const float*)d_in[12];
  const float* mlp_w2  = (const float*)d_in[13];
  const int* species   = (const int*)d_in[14];
  const int* senders   = (const int*)d_in[15];
  const int* receivers = (const int*)d_in[16];
  float* out = (float*)d_out;

  int N = in_sizes[14];
  int E = in_sizes[15];

  float* ws = (float*)d_ws;
  size_t o = 0;
  float* agg0 = ws + o;  o += (size_t)N * 1024;
  float* agg1 = ws + o;  o += (size_t)N * 1024;
  float* up0  = ws + o;  o += (size_t)N * 64;
  float* up1  = ws + o;  o += (size_t)N * 256;
  float* resb = ws + o;  o += (size_t)N * 64;
  float* pack1 = ws + o; o += 16384;
  float* pack2 = ws + o; o += 32768;
  int* row_start = (int*)(ws + o); o += (size_t)N + 1;
  int* cursor    = (int*)(ws + o); o += (size_t)N;
  int* perm      = (int*)(ws + o); o += (size_t)E;
  int* rsort     = (int*)(ws + o); o += (size_t)E;

  // zero scatter targets + histogram counters
  hipMemsetAsync(agg0, 0, (size_t)N * 2048 * sizeof(float), stream);
  hipMemsetAsync(cursor, 0, (size_t)N * sizeof(int), stream);

  // CSR build (shared by both interactions)
  k_hist<<<(E + 255) / 256, 256, 0, stream>>>(receivers, cursor, E);
  k_scan<<<1, 256, 0, stream>>>(cursor, row_start, cursor, N);
  k_scatter<<<(E + 255) / 256, 256, 0, stream>>>(receivers, cursor, perm, rsort, E);

  k_pack<<<16, 256, 0, stream>>>(rw2, pack1, pack2);
  k_up0<<<(N + 3) / 4, 256, 0, stream>>>(embed, lu0, species, up0, N);

  int eblocks = (E + 4 * CHUNK - 1) / (4 * CHUNK);
  k_edge1<<<eblocks, 256, 0, stream>>>(ev, rw1, pack1, up0, senders, perm, rsort, agg0, E);
  k_node1<<<N, 64, 0, stream>>>(agg0, ld, sel_w, pw0, res_w, lu1, read0, species,
                                out, resb, up1, N);
  k_edge2<<<eblocks, 256, 0, stream>>>(ev, rw1 + 512, pack2, up1, senders, perm, rsort, agg1, E);
  k_node2<<<N, 64, 0, stream>>>(agg1, ld + 16384, pw1, resb, mlp_w1, mlp_w2, species, out, N);
}

// Round 3
// 759.305 us; speedup vs baseline: 2.0863x; 1.8612x over previous
//
#include <hip/hip_runtime.h>
#include <math.h>

// MACE-like block. CSR-sorted edges + f16 MFMA for the radial R-GEMM fused
// with message/aggregation (R lives only in LDS).
// N=10000 nodes, E=160000 edges, C=64, 16 sph, S=10 species.

typedef _Float16 half8 __attribute__((ext_vector_type(8)));
typedef float f32x4 __attribute__((ext_vector_type(4)));

__device__ __forceinline__ float silu_f(float x) { return x / (1.0f + expf(-x)); }

__device__ __forceinline__ float reduce64(float v) {
#pragma unroll
  for (int off = 32; off > 0; off >>= 1) v += __shfl_xor(v, off, 64);
  return v;
}

__device__ __forceinline__ void compute_Y(float x, float y, float z, float* Y) {
  float x2 = x * x, y2 = y * y, z2 = z * z;
  Y[0] = 1.0f;
  Y[1] = 1.7320508f * x;
  Y[2] = 1.7320508f * y;
  Y[3] = 1.7320508f * z;
  Y[4] = 3.8729833f * x * y;
  Y[5] = 3.8729833f * y * z;
  Y[6] = 1.118034f * (3.0f * z2 - 1.0f);
  Y[7] = 3.8729833f * x * z;
  Y[8] = 1.9364917f * (x2 - y2);
  Y[9] = 2.09165f * y * (3.0f * x2 - y2);
  Y[10] = 10.246951f * x * y * z;
  Y[11] = 1.6201852f * y * (5.0f * z2 - 1.0f);
  Y[12] = 1.3228757f * z * (5.0f * z2 - 3.0f);
  Y[13] = 1.6201852f * x * (5.0f * z2 - 1.0f);
  Y[14] = 5.1234753f * z * (x2 - y2);
  Y[15] = 2.09165f * x * (x2 - 3.0f * y2);
}

__device__ __forceinline__ void compute_rb(float r, float inv_r, float* rb) {
  float t = fminf(r * 0.2f, 1.0f);
  float t2 = t * t;
  float t5 = t2 * t2 * t;
  float env = 1.0f + t5 * (-21.0f + t * (35.0f - 15.0f * t));
  float th = 0.62831853f * r;  // pi*r/5
  float s1 = sinf(th), c1 = cosf(th);
  float c2 = 2.0f * c1;
  float sprev = 0.0f, scur = s1;
  float coef = 0.63245553f * inv_r * env;
#pragma unroll
  for (int k = 0; k < 8; k++) {
    rb[k] = coef * scur;
    float snxt = c2 * scur - sprev;
    sprev = scur; scur = snxt;
  }
}

__device__ __forceinline__ int l_of_m(int m) {
  return (m == 0) ? 0 : ((m < 4) ? 1 : ((m < 9) ? 2 : 3));
}

// ---------------------------------------------------------------- CSR build
__global__ __launch_bounds__(256) void k_hist(const int* __restrict__ receivers,
                                              int* __restrict__ cnt, int E) {
  int e = blockIdx.x * 256 + threadIdx.x;
  if (e < E) atomicAdd(&cnt[receivers[e]], 1);
}

__global__ __launch_bounds__(256) void k_scan(const int* __restrict__ deg,
                                              int* __restrict__ row_start,
                                              int* __restrict__ cursor, int N) {
  __shared__ int part[256];
  int t = threadIdx.x;
  int K = (N + 255) / 256;
  int lo = t * K, hi = min(lo + K, N);
  int s = 0;
  for (int i = lo; i < hi; i++) s += deg[i];
  part[t] = s;
  __syncthreads();
  for (int d = 1; d < 256; d <<= 1) {
    int v = (t >= d) ? part[t - d] : 0;
    __syncthreads();
    part[t] += v;
    __syncthreads();
  }
  int run = (t == 0) ? 0 : part[t - 1];
  for (int i = lo; i < hi; i++) {
    int di = deg[i];            // deg aliases cursor; read before overwrite
    row_start[i] = run;
    cursor[i] = run;
    run += di;
  }
  if (t == 255) row_start[N] = part[255];
}

__global__ __launch_bounds__(256) void k_scatter(const int* __restrict__ receivers,
                                                 const int* __restrict__ senders,
                                                 int* __restrict__ cursor,
                                                 int* __restrict__ perm,
                                                 int* __restrict__ rsort,
                                                 int* __restrict__ ssort, int E) {
  int e = blockIdx.x * 256 + threadIdx.x;
  if (e < E) {
    int r = receivers[e];
    int pos = atomicAdd(&cursor[r], 1);
    perm[pos] = e;
    rsort[pos] = r;
    ssort[pos] = senders[e];
  }
}

// ---------------------------------------------------------------- pack rw2 -> f16 B^T
// b1t[n][k], n = c*4+j (j=0..3), 256x64.  b2t[n][k], n = c*6+j, cols {0,1,2,3,5,9}, 384x64.
__global__ __launch_bounds__(256) void k_pack(const float* __restrict__ rw2,
                                              _Float16* __restrict__ b1t,
                                              _Float16* __restrict__ b2t) {
  int idx = blockIdx.x * 256 + threadIdx.x;
  if (idx < 16384) {
    int n = idx >> 6, k = idx & 63;
    int c = n >> 2, j = n & 3;
    b1t[idx] = (_Float16)rw2[k * 768 + c * 12 + j];
  } else if (idx < 40960) {
    int i2 = idx - 16384;
    int n = i2 >> 6, k = i2 & 63;
    int c = n / 6, j = n - c * 6;
    int col = (j < 4) ? j : ((j == 4) ? 5 : 9);
    b2t[i2] = (_Float16)rw2[49152 + k * 768 + c * 12 + col];
  }
}

// ---------------------------------------------------------------- up0
__global__ __launch_bounds__(256) void k_up0(const float* __restrict__ embed,
                                             const float* __restrict__ lu0,
                                             const int* __restrict__ species,
                                             float* __restrict__ up0, int N) {
  int wave = threadIdx.x >> 6, lane = threadIdx.x & 63;
  int n = (blockIdx.x << 2) + wave;
  if (n >= N) return;
  int sp = species[n];
  const float* er = embed + sp * 64;
  float acc = 0.0f;
#pragma unroll 8
  for (int c = 0; c < 64; c++) acc += er[c] * lu0[c * 64 + lane];
  up0[(size_t)n * 64 + lane] = acc;
}

// ---------------------------------------------------------------- geometry (sorted order)
// wave per sorted edge j: Y -> Ysort[j][16]; both radial hiddens -> f16 rows.
__global__ __launch_bounds__(256) void k_geom(const float* __restrict__ ev,
                                              const float* __restrict__ rw1,
                                              const int* __restrict__ perm,
                                              _Float16* __restrict__ hid0,
                                              _Float16* __restrict__ hid1,
                                              float* __restrict__ Ysort,
                                              int E, int EPAD) {
  int wave = threadIdx.x >> 6, lane = threadIdx.x & 63;
  int j = blockIdx.x * 4 + wave;
  if (j >= EPAD) return;
  if (j >= E) {
    hid0[(size_t)j * 64 + lane] = (_Float16)0.0f;
    hid1[(size_t)j * 64 + lane] = (_Float16)0.0f;
    return;
  }
  int e = perm[j];
  float vx = ev[e * 3 + 0], vy = ev[e * 3 + 1], vz = ev[e * 3 + 2];
  float r = sqrtf(vx * vx + vy * vy + vz * vz);
  float inv_r = 1.0f / (r + 1e-8f);
  float Y[16]; compute_Y(vx * inv_r, vy * inv_r, vz * inv_r, Y);
  float rb[8]; compute_rb(r, inv_r, rb);

  float h0 = 0.0f, h1 = 0.0f;
#pragma unroll
  for (int k = 0; k < 8; k++) {
    h0 += rb[k] * rw1[k * 64 + lane];
    h1 += rb[k] * rw1[512 + k * 64 + lane];
  }
  hid0[(size_t)j * 64 + lane] = (_Float16)silu_f(h0);
  hid1[(size_t)j * 64 + lane] = (_Float16)silu_f(h1);
  if (lane == 0) {
#pragma unroll
    for (int m = 0; m < 16; m++) Ysort[(size_t)j * 16 + m] = Y[m];
  }
}

// ---------------------------------------------------------------- fused MFMA + agg, pass 1
// Per wave: 2 tiles of 16 sorted edges. Stage1: MFMA R[16][256] -> LDS (f16).
// Stage2: per-edge messages, register run-accumulation, atomic flush on receiver change.
// No __syncthreads needed: each wave owns its LDS slice.
__global__ __launch_bounds__(256) void k_fagg1(const _Float16* __restrict__ hid,
                                               const _Float16* __restrict__ bt,
                                               const float* __restrict__ Ysort,
                                               const float* __restrict__ up0,
                                               const int* __restrict__ ssort,
                                               const int* __restrict__ rsort,
                                               float* __restrict__ agg, int E) {
  __shared__ _Float16 __attribute__((aligned(16))) lds[4][16 * 256];  // 32 KB
  int wave = threadIdx.x >> 6, lane = threadIdx.x & 63;
  int q = lane >> 4, mr = lane & 15;
  _Float16* L = lds[wave];
  int jbase = (blockIdx.x * 4 + wave) * 32;
  float accm[16];
#pragma unroll
  for (int m = 0; m < 16; m++) accm[m] = 0.0f;
  int cur_r = (jbase < E) ? rsort[jbase] : -1;

  for (int hf = 0; hf < 2; hf++) {
    int j0 = jbase + hf * 16;
    // stage 1
    const half8* Ap = (const half8*)(hid + (size_t)(j0 + mr) * 64 + q * 8);
    half8 a0 = Ap[0];
    half8 a1 = Ap[4];  // +32 halves
    const _Float16* bp = bt + (size_t)mr * 64 + q * 8;
#pragma unroll
    for (int T = 0; T < 16; T++) {
      half8 b0 = *(const half8*)(bp + T * 1024);
      half8 b1 = *(const half8*)(bp + T * 1024 + 32);
      f32x4 acc = {0.f, 0.f, 0.f, 0.f};
      acc = __builtin_amdgcn_mfma_f32_16x16x32_f16(a0, b0, acc, 0, 0, 0);
      acc = __builtin_amdgcn_mfma_f32_16x16x32_f16(a1, b1, acc, 0, 0, 0);
#pragma unroll
      for (int r = 0; r < 4; r++)
        L[(q * 4 + r) * 256 + T * 16 + mr] = (_Float16)acc[r];
    }
    // stage 2
    for (int t = 0; t < 16; t++) {
      int j = j0 + t;
      bool ok = (j < E);
      int rr = ok ? rsort[j] : -2;
      if (rr != cur_r) {
        if (cur_r >= 0) {
          float* base = agg + ((size_t)cur_r << 10) + lane;
#pragma unroll
          for (int m = 0; m < 16; m++) atomicAdd(base + (m << 6), accm[m]);
        }
#pragma unroll
        for (int m = 0; m < 16; m++) accm[m] = 0.0f;
        cur_r = rr;
      }
      if (ok) {
        int s = ssort[j];
        float hs0 = up0[(size_t)s * 64 + lane];
        const _Float16* Rr = L + t * 256 + lane * 4;
        float p0 = (float)Rr[0] * hs0, p1 = (float)Rr[1] * hs0;
        float p2 = (float)Rr[2] * hs0, p3 = (float)Rr[3] * hs0;
        float Yv = Ysort[(size_t)j * 16 + mr];
        accm[0] += p0;  // Y[0] = 1
#pragma unroll
        for (int m = 1; m < 16; m++) {
          float Ym = __shfl(Yv, m, 64);
          float pm = (m < 4) ? p1 : ((m < 9) ? p2 : p3);
          accm[m] += pm * Ym;
        }
      }
    }
  }
  if (cur_r >= 0) {
    float* base = agg + ((size_t)cur_r << 10) + lane;
#pragma unroll
    for (int m = 0; m < 16; m++) atomicAdd(base + (m << 6), accm[m]);
  }
}

// ---------------------------------------------------------------- fused MFMA + agg, pass 2
// N = 384 cols (c*6+j), LDS 12 KB/wave.
__global__ __launch_bounds__(256) void k_fagg2(const _Float16* __restrict__ hid,
                                               const _Float16* __restrict__ bt,
                                               const float* __restrict__ Ysort,
                                               const float* __restrict__ up1,
                                               const int* __restrict__ ssort,
                                               const int* __restrict__ rsort,
                                               float* __restrict__ agg, int E) {
  __shared__ _Float16 __attribute__((aligned(16))) lds[4][16 * 384];  // 48 KB
  int wave = threadIdx.x >> 6, lane = threadIdx.x & 63;
  int q = lane >> 4, mr = lane & 15;
  _Float16* L = lds[wave];
  int jbase = (blockIdx.x * 4 + wave) * 32;
  float accm[16];
#pragma unroll
  for (int m = 0; m < 16; m++) accm[m] = 0.0f;
  int cur_r = (jbase < E) ? rsort[jbase] : -1;

  for (int hf = 0; hf < 2; hf++) {
    int j0 = jbase + hf * 16;
    // stage 1
    const half8* Ap = (const half8*)(hid + (size_t)(j0 + mr) * 64 + q * 8);
    half8 a0 = Ap[0];
    half8 a1 = Ap[4];
    const _Float16* bp = bt + (size_t)mr * 64 + q * 8;
#pragma unroll
    for (int T = 0; T < 24; T++) {
      half8 b0 = *(const half8*)(bp + T * 1024);
      half8 b1 = *(const half8*)(bp + T * 1024 + 32);
      f32x4 acc = {0.f, 0.f, 0.f, 0.f};
      acc = __builtin_amdgcn_mfma_f32_16x16x32_f16(a0, b0, acc, 0, 0, 0);
      acc = __builtin_amdgcn_mfma_f32_16x16x32_f16(a1, b1, acc, 0, 0, 0);
#pragma unroll
      for (int r = 0; r < 4; r++)
        L[(q * 4 + r) * 384 + T * 16 + mr] = (_Float16)acc[r];
    }
    // stage 2
    for (int t = 0; t < 16; t++) {
      int j = j0 + t;
      bool ok = (j < E);
      int rr = ok ? rsort[j] : -2;
      if (rr != cur_r) {
        if (cur_r >= 0) {
          float* base = agg + ((size_t)cur_r << 10) + lane;
#pragma unroll
          for (int m = 0; m < 16; m++) atomicAdd(base + (m << 6), accm[m]);
        }
#pragma unroll
        for (int m = 0; m < 16; m++) accm[m] = 0.0f;
        cur_r = rr;
      }
      if (ok) {
        int s = ssort[j];
        const float* hp = up1 + ((size_t)s << 8) + lane;
        float hs0 = hp[0], hs1 = hp[64], hs2 = hp[128], hs3 = hp[192];
        const _Float16* Rr = L + t * 384 + lane * 6;
        float R0 = (float)Rr[0], R1v = (float)Rr[1];
        float R2v = (float)Rr[2], R3v = (float)Rr[3];
        float c5 = (float)Rr[4], c9 = (float)Rr[5];
        float q0 = R0 * hs0, q1 = R1v * hs0, q2 = R2v * hs0, q3 = R3v * hs0;
        float Yv = Ysort[(size_t)j * 16 + mr];
        float Y1 = __shfl(Yv, 1, 64), Y2 = __shfl(Yv, 2, 64), Y3 = __shfl(Yv, 3, 64);
        accm[0] += q0 + c9 * (hs1 * Y1 + hs2 * Y2 + hs3 * Y3);
        accm[1] += q1 * Y1 + c5 * hs1;
        accm[2] += q1 * Y2 + c5 * hs2;
        accm[3] += q1 * Y3 + c5 * hs3;
#pragma unroll
        for (int m = 4; m < 9; m++)  accm[m] += q2 * __shfl(Yv, m, 64);
#pragma unroll
        for (int m = 9; m < 16; m++) accm[m] += q3 * __shfl(Yv, m, 64);
      }
    }
  }
  if (cur_r >= 0) {
    float* base = agg + ((size_t)cur_r << 10) + lane;
#pragma unroll
    for (int m = 0; m < 16; m++) atomicAdd(base + (m << 6), accm[m]);
  }
}

// ---------------------------------------------------------------- node kernel 1
__global__ __launch_bounds__(64) void k_node1(const float* __restrict__ agg0,
                                              const float* __restrict__ ld0,
                                              const float* __restrict__ sel_w,
                                              const float* __restrict__ pw0,
                                              const float* __restrict__ res_w,
                                              const float* __restrict__ lu1,
                                              const float* __restrict__ read0,
                                              const int* __restrict__ species,
                                              float* __restrict__ out,
                                              float* __restrict__ res,
                                              float* __restrict__ up1, int N) {
  int n = blockIdx.x, d = threadIdx.x;
  int sp = species[n];
  __shared__ float sA[1024], sB[1024];

  const float* ag = agg0 + ((size_t)n << 10);
#pragma unroll
  for (int m = 0; m < 16; m++) sA[m * 64 + d] = ag[m * 64 + d] * 0.0625f;
  __syncthreads();

  float fr[16];
  for (int m = 0; m < 16; m++) {
    const float* W = ld0 + l_of_m(m) * 4096 + d;
    float a = 0.0f;
#pragma unroll 16
    for (int c = 0; c < 64; c++) a += sA[m * 64 + c] * W[c * 64];
    fr[m] = a;
  }
#pragma unroll
  for (int m = 0; m < 16; m++) sB[m * 64 + d] = fr[m];
  __syncthreads();

  float f2r[16];
  for (int m = 0; m < 16; m++) {
    const float* W = sel_w + ((size_t)(sp * 4 + l_of_m(m)) << 12) + d;
    float a = 0.0f;
#pragma unroll 16
    for (int c = 0; c < 64; c++) a += sB[m * 64 + c] * W[c * 64];
    f2r[m] = a;
  }
  float s0 = f2r[0];
  float tt = 1.0f + s0 + s0 * s0;
#pragma unroll
  for (int m = 0; m < 4; m++) sA[m * 64 + d] = f2r[m] * tt;
  __syncthreads();

  float f1r[4];
  for (int m = 0; m < 4; m++) {
    const float* W = pw0 + ((size_t)sp << 12) + d;
    float a = 0.0f;
#pragma unroll 16
    for (int c = 0; c < 64; c++) a += sA[m * 64 + c] * W[c * 64];
    f1r[m] = a;
  }
#pragma unroll
  for (int m = 0; m < 4; m++) sB[m * 64 + d] = f1r[m];
  __syncthreads();

  float v = reduce64(f1r[0] * read0[d]);
  if (d == 0) out[2 * n] = v;

  {
    const float* W = res_w + ((size_t)sp << 12) + d;
    float a = 0.0f;
#pragma unroll 16
    for (int c = 0; c < 64; c++) a += sB[c] * W[c * 64];
    res[(size_t)n * 64 + d] = a;
  }
  {
    float a = 0.0f;
#pragma unroll 16
    for (int c = 0; c < 64; c++) a += sB[c] * lu1[c * 64 + d];
    up1[((size_t)n << 8) + d] = a;
  }
  for (int m = 1; m < 4; m++) {
    float a = 0.0f;
#pragma unroll 16
    for (int c = 0; c < 64; c++) a += sB[m * 64 + c] * lu1[4096 + c * 64 + d];
    up1[((size_t)n << 8) + (m << 6) + d] = a;
  }
}

// ---------------------------------------------------------------- node kernel 2
__global__ __launch_bounds__(64) void k_node2(const float* __restrict__ agg1,
                                              const float* __restrict__ ld1,
                                              const float* __restrict__ pw1,
                                              const float* __restrict__ res,
                                              const float* __restrict__ mlp_w1,
                                              const float* __restrict__ mlp_w2,
                                              const int* __restrict__ species,
                                              float* __restrict__ out, int N) {
  int n = blockIdx.x, d = threadIdx.x;
  int sp = species[n];
  __shared__ float sA[1024];

  const float* ag = agg1 + ((size_t)n << 10);
#pragma unroll
  for (int m = 0; m < 16; m++) sA[m * 64 + d] = ag[m * 64 + d] * 0.0625f;
  __syncthreads();

  float g[16];
  for (int m = 0; m < 16; m++) {
    const float* W = ld1 + l_of_m(m) * 4096 + d;
    float a = 0.0f;
#pragma unroll 16
    for (int c = 0; c < 64; c++) a += sA[m * 64 + c] * W[c * 64];
    g[m] = a;
  }
  float inv = g[0];
#pragma unroll
  for (int m = 1; m < 16; m++) inv += g[m] * g[m];
  float q = inv + inv * inv;
  __syncthreads();
  sA[d] = q;
  __syncthreads();

  float a = res[(size_t)n * 64 + d];
  {
    const float* W = pw1 + ((size_t)sp << 12) + d;
#pragma unroll 16
    for (int c = 0; c < 64; c++) a += sA[c] * W[c * 64];
  }
  sA[64 + d] = a;
  __syncthreads();

  float val = 0.0f;
  if (d < 32) {
    float h = 0.0f;
#pragma unroll 16
    for (int c = 0; c < 64; c++) h += sA[64 + c] * mlp_w1[c * 32 + d];
    val = silu_f(h) * mlp_w2[d];
  }
  val = reduce64(val);
  if (d == 0) out[2 * n + 1] = val;
}

// ---------------------------------------------------------------- launch
extern "C" void kernel_launch(void* const* d_in, const int* in_sizes, int n_in,
                              void* d_out, int out_size, void* d_ws, size_t ws_size,
                              hipStream_t stream) {
  const float* ev      = (const float*)d_in[0];
  const float* embed   = (const float*)d_in[1];
  const float* rw1     = (const float*)d_in[2];
  const float* rw2     = (const float*)d_in[3];
  const float* lu0     = (const float*)d_in[4];
  const float* lu1     = (const float*)d_in[5];
  const float* ld      = (const float*)d_in[6];
  const float* sel_w   = (const float*)d_in[7];
  const float* pw0     = (const float*)d_in[8];
  const float* pw1     = (const float*)d_in[9];
  const float* res_w   = (const float*)d_in[10];
  const float* read0   = (const float*)d_in[11];
  const float* mlp_w1  = (const float*)d_in[12];
  const float* mlp_w2  = (const float*)d_in[13];
  const int* species   = (const int*)d_in[14];
  const int* senders   = (const int*)d_in[15];
  const int* receivers = (const int*)d_in[16];
  float* out = (float*)d_out;

  int N = in_sizes[14];
  int E = in_sizes[15];
  int EPAD = ((E + 127) / 128) * 128;

  float* ws = (float*)d_ws;
  size_t o = 0;
  float* agg  = ws + o;  o += (size_t)N * 1024;   // shared by both interactions
  float* up0  = ws + o;  o += (size_t)N * 64;
  float* up1  = ws + o;  o += (size_t)N * 256;
  float* resb = ws + o;  o += (size_t)N * 64;
  _Float16* b1t  = (_Float16*)(ws + o); o += 8192;          // 256x64 f16
  _Float16* b2t  = (_Float16*)(ws + o); o += 12288;         // 384x64 f16
  _Float16* hid0 = (_Float16*)(ws + o); o += (size_t)EPAD * 32;
  _Float16* hid1 = (_Float16*)(ws + o); o += (size_t)EPAD * 32;
  float* Ysort = ws + o; o += (size_t)E * 16;
  int* row_start = (int*)(ws + o); o += (size_t)N + 1;
  int* cursor    = (int*)(ws + o); o += (size_t)N;
  int* perm      = (int*)(ws + o); o += (size_t)E;
  int* rsort     = (int*)(ws + o); o += (size_t)E;
  int* ssort     = (int*)(ws + o); o += (size_t)E;

  hipMemsetAsync(agg, 0, (size_t)N * 1024 * sizeof(float), stream);
  hipMemsetAsync(cursor, 0, (size_t)N * sizeof(int), stream);

  // CSR build (shared by both interactions)
  k_hist<<<(E + 255) / 256, 256, 0, stream>>>(receivers, cursor, E);
  k_scan<<<1, 256, 0, stream>>>(cursor, row_start, cursor, N);
  k_scatter<<<(E + 255) / 256, 256, 0, stream>>>(receivers, senders, cursor,
                                                 perm, rsort, ssort, E);

  k_pack<<<160, 256, 0, stream>>>(rw2, b1t, b2t);
  k_up0<<<(N + 3) / 4, 256, 0, stream>>>(embed, lu0, species, up0, N);
  k_geom<<<EPAD / 4, 256, 0, stream>>>(ev, rw1, perm, hid0, hid1, Ysort, E, EPAD);

  int fblocks = (E + 127) / 128;   // 4 waves x 32 edges per block
  k_fagg1<<<fblocks, 256, 0, stream>>>(hid0, b1t, Ysort, up0, ssort, rsort, agg, E);
  k_node1<<<N, 64, 0, stream>>>(agg, ld, sel_w, pw0, res_w, lu1, read0, species,
                                out, resb, up1, N);
  hipMemsetAsync(agg, 0, (size_t)N * 1024 * sizeof(float), stream);
  k_fagg2<<<fblocks, 256, 0, stream>>>(hid1, b2t, Ysort, up1, ssort, rsort, agg, E);
  k_node2<<<N, 64, 0, stream>>>(agg, ld + 16384, pw1, resb, mlp_w1, mlp_w2, species, out, N);
}

// Round 4
// 578.580 us; speedup vs baseline: 2.7379x; 1.3124x over previous
//
#include <hip/hip_runtime.h>
#include <math.h>

// MACE-like block. CSR-sorted edges + f16 MFMA R-GEMM fused with aggregation.
// R4: 16 edges/wave (2.4x parallelism), wave-uniform Y loads (no shuffles),
//     l-group weight reuse in node kernels, node1 zeroes agg in-place.
// N=10000 nodes, E=160000 edges, C=64, 16 sph, S=10 species.

typedef _Float16 half8 __attribute__((ext_vector_type(8)));
typedef float f32x4 __attribute__((ext_vector_type(4)));

__device__ __forceinline__ float silu_f(float x) { return x / (1.0f + expf(-x)); }

__device__ __forceinline__ float reduce64(float v) {
#pragma unroll
  for (int off = 32; off > 0; off >>= 1) v += __shfl_xor(v, off, 64);
  return v;
}

__device__ __forceinline__ void compute_Y(float x, float y, float z, float* Y) {
  float x2 = x * x, y2 = y * y, z2 = z * z;
  Y[0] = 1.0f;
  Y[1] = 1.7320508f * x;
  Y[2] = 1.7320508f * y;
  Y[3] = 1.7320508f * z;
  Y[4] = 3.8729833f * x * y;
  Y[5] = 3.8729833f * y * z;
  Y[6] = 1.118034f * (3.0f * z2 - 1.0f);
  Y[7] = 3.8729833f * x * z;
  Y[8] = 1.9364917f * (x2 - y2);
  Y[9] = 2.09165f * y * (3.0f * x2 - y2);
  Y[10] = 10.246951f * x * y * z;
  Y[11] = 1.6201852f * y * (5.0f * z2 - 1.0f);
  Y[12] = 1.3228757f * z * (5.0f * z2 - 3.0f);
  Y[13] = 1.6201852f * x * (5.0f * z2 - 1.0f);
  Y[14] = 5.1234753f * z * (x2 - y2);
  Y[15] = 2.09165f * x * (x2 - 3.0f * y2);
}

__device__ __forceinline__ void compute_rb(float r, float inv_r, float* rb) {
  float t = fminf(r * 0.2f, 1.0f);
  float t2 = t * t;
  float t5 = t2 * t2 * t;
  float env = 1.0f + t5 * (-21.0f + t * (35.0f - 15.0f * t));
  float th = 0.62831853f * r;  // pi*r/5
  float s1 = sinf(th), c1 = cosf(th);
  float c2 = 2.0f * c1;
  float sprev = 0.0f, scur = s1;
  float coef = 0.63245553f * inv_r * env;
#pragma unroll
  for (int k = 0; k < 8; k++) {
    rb[k] = coef * scur;
    float snxt = c2 * scur - sprev;
    sprev = scur; scur = snxt;
  }
}

// ---------------------------------------------------------------- CSR build
__global__ __launch_bounds__(256) void k_hist(const int* __restrict__ receivers,
                                              int* __restrict__ cnt, int E) {
  int e = blockIdx.x * 256 + threadIdx.x;
  if (e < E) atomicAdd(&cnt[receivers[e]], 1);
}

__global__ __launch_bounds__(256) void k_scan(const int* __restrict__ deg,
                                              int* __restrict__ row_start,
                                              int* __restrict__ cursor, int N) {
  __shared__ int part[256];
  int t = threadIdx.x;
  int K = (N + 255) / 256;
  int lo = t * K, hi = min(lo + K, N);
  int s = 0;
  for (int i = lo; i < hi; i++) s += deg[i];
  part[t] = s;
  __syncthreads();
  for (int d = 1; d < 256; d <<= 1) {
    int v = (t >= d) ? part[t - d] : 0;
    __syncthreads();
    part[t] += v;
    __syncthreads();
  }
  int run = (t == 0) ? 0 : part[t - 1];
  for (int i = lo; i < hi; i++) {
    int di = deg[i];            // deg aliases cursor; read before overwrite
    row_start[i] = run;
    cursor[i] = run;
    run += di;
  }
  if (t == 255) row_start[N] = part[255];
}

__global__ __launch_bounds__(256) void k_scatter(const int* __restrict__ receivers,
                                                 const int* __restrict__ senders,
                                                 int* __restrict__ cursor,
                                                 int* __restrict__ perm,
                                                 int* __restrict__ rsort,
                                                 int* __restrict__ ssort, int E) {
  int e = blockIdx.x * 256 + threadIdx.x;
  if (e < E) {
    int r = receivers[e];
    int pos = atomicAdd(&cursor[r], 1);
    perm[pos] = e;
    rsort[pos] = r;
    ssort[pos] = senders[e];
  }
}

// ---------------------------------------------------------------- pack rw2 -> f16 B^T
__global__ __launch_bounds__(256) void k_pack(const float* __restrict__ rw2,
                                              _Float16* __restrict__ b1t,
                                              _Float16* __restrict__ b2t) {
  int idx = blockIdx.x * 256 + threadIdx.x;
  if (idx < 16384) {
    int n = idx >> 6, k = idx & 63;
    int c = n >> 2, j = n & 3;
    b1t[idx] = (_Float16)rw2[k * 768 + c * 12 + j];
  } else if (idx < 40960) {
    int i2 = idx - 16384;
    int n = i2 >> 6, k = i2 & 63;
    int c = n / 6, j = n - c * 6;
    int col = (j < 4) ? j : ((j == 4) ? 5 : 9);
    b2t[i2] = (_Float16)rw2[49152 + k * 768 + c * 12 + col];
  }
}

// ---------------------------------------------------------------- up0
__global__ __launch_bounds__(256) void k_up0(const float* __restrict__ embed,
                                             const float* __restrict__ lu0,
                                             const int* __restrict__ species,
                                             float* __restrict__ up0, int N) {
  int wave = threadIdx.x >> 6, lane = threadIdx.x & 63;
  int n = (blockIdx.x << 2) + wave;
  if (n >= N) return;
  int sp = species[n];
  const float* er = embed + sp * 64;
  float acc = 0.0f;
#pragma unroll 8
  for (int c = 0; c < 64; c++) acc += er[c] * lu0[c * 64 + lane];
  up0[(size_t)n * 64 + lane] = acc;
}

// ---------------------------------------------------------------- geometry (sorted order)
__global__ __launch_bounds__(256) void k_geom(const float* __restrict__ ev,
                                              const float* __restrict__ rw1,
                                              const int* __restrict__ perm,
                                              _Float16* __restrict__ hid0,
                                              _Float16* __restrict__ hid1,
                                              float* __restrict__ Ysort,
                                              int E, int EPAD) {
  int wave = threadIdx.x >> 6, lane = threadIdx.x & 63;
  int j = blockIdx.x * 4 + wave;
  if (j >= EPAD) return;
  if (j >= E) {
    hid0[(size_t)j * 64 + lane] = (_Float16)0.0f;
    hid1[(size_t)j * 64 + lane] = (_Float16)0.0f;
    return;
  }
  int e = perm[j];
  float vx = ev[e * 3 + 0], vy = ev[e * 3 + 1], vz = ev[e * 3 + 2];
  float r = sqrtf(vx * vx + vy * vy + vz * vz);
  float inv_r = 1.0f / (r + 1e-8f);
  float Y[16]; compute_Y(vx * inv_r, vy * inv_r, vz * inv_r, Y);
  float rb[8]; compute_rb(r, inv_r, rb);

  float h0 = 0.0f, h1 = 0.0f;
#pragma unroll
  for (int k = 0; k < 8; k++) {
    h0 += rb[k] * rw1[k * 64 + lane];
    h1 += rb[k] * rw1[512 + k * 64 + lane];
  }
  hid0[(size_t)j * 64 + lane] = (_Float16)silu_f(h0);
  hid1[(size_t)j * 64 + lane] = (_Float16)silu_f(h1);

  // lane m (m<16) stores Y[m]; select without dynamic index (avoid scratch)
  float yv = Y[0];
#pragma unroll
  for (int m = 1; m < 16; m++) yv = (lane == m) ? Y[m] : yv;
  if (lane < 16) Ysort[(size_t)j * 16 + lane] = yv;
}

// ---------------------------------------------------------------- fused MFMA + agg, pass 1
// One 16-edge tile per wave. Stage1: MFMA R[16][256] -> LDS f16 (per-wave slice,
// no barriers). Stage2: per-edge messages with wave-uniform Y float4 loads,
// register run-accumulation, atomic flush on receiver change.
__global__ __launch_bounds__(256) void k_fagg1(const _Float16* __restrict__ hid,
                                               const _Float16* __restrict__ bt,
                                               const float* __restrict__ Ysort,
                                               const float* __restrict__ up0,
                                               const int* __restrict__ ssort,
                                               const int* __restrict__ rsort,
                                               float* __restrict__ agg,
                                               int E, int EPAD) {
  __shared__ _Float16 __attribute__((aligned(16))) lds[4][16 * 256];  // 32 KB
  int wave = threadIdx.x >> 6, lane = threadIdx.x & 63;
  int q = lane >> 4, mr = lane & 15;
  _Float16* L = lds[wave];
  int j0 = (blockIdx.x * 4 + wave) * 16;
  if (j0 >= EPAD) return;

  // stage 1
  const half8* Ap = (const half8*)(hid + (size_t)(j0 + mr) * 64 + q * 8);
  half8 a0 = Ap[0];
  half8 a1 = Ap[4];  // +32 halves
  const _Float16* bp = bt + (size_t)mr * 64 + q * 8;
#pragma unroll
  for (int T = 0; T < 16; T++) {
    half8 b0 = *(const half8*)(bp + T * 1024);
    half8 b1 = *(const half8*)(bp + T * 1024 + 32);
    f32x4 acc = {0.f, 0.f, 0.f, 0.f};
    acc = __builtin_amdgcn_mfma_f32_16x16x32_f16(a0, b0, acc, 0, 0, 0);
    acc = __builtin_amdgcn_mfma_f32_16x16x32_f16(a1, b1, acc, 0, 0, 0);
#pragma unroll
    for (int r = 0; r < 4; r++)
      L[(q * 4 + r) * 256 + T * 16 + mr] = (_Float16)acc[r];
  }

  // stage 2
  float accm[16];
#pragma unroll
  for (int m = 0; m < 16; m++) accm[m] = 0.0f;
  int cur_r = (j0 < E) ? rsort[j0] : -1;

  for (int t = 0; t < 16; t++) {
    int j = j0 + t;
    bool ok = (j < E);
    int rr = ok ? rsort[j] : -2;
    if (rr != cur_r) {         // wave-uniform
      if (cur_r >= 0) {
        float* base = agg + ((size_t)cur_r << 10) + lane;
#pragma unroll
        for (int m = 0; m < 16; m++) atomicAdd(base + (m << 6), accm[m]);
      }
#pragma unroll
      for (int m = 0; m < 16; m++) accm[m] = 0.0f;
      cur_r = rr;
    }
    if (ok) {
      int s = ssort[j];
      float hs0 = up0[(size_t)s * 64 + lane];
      const _Float16* Rr = L + t * 256 + lane * 4;
      float p0 = (float)Rr[0] * hs0, p1 = (float)Rr[1] * hs0;
      float p2 = (float)Rr[2] * hs0, p3 = (float)Rr[3] * hs0;
      const float* Yj = Ysort + (size_t)j * 16;   // wave-uniform address
      float4 Ya = *(const float4*)(Yj);
      float4 Yb = *(const float4*)(Yj + 4);
      float4 Yc = *(const float4*)(Yj + 8);
      float4 Yd = *(const float4*)(Yj + 12);
      accm[0] += p0;
      accm[1] += p1 * Ya.y;  accm[2] += p1 * Ya.z;  accm[3] += p1 * Ya.w;
      accm[4] += p2 * Yb.x;  accm[5] += p2 * Yb.y;  accm[6] += p2 * Yb.z;
      accm[7] += p2 * Yb.w;  accm[8] += p2 * Yc.x;
      accm[9]  += p3 * Yc.y; accm[10] += p3 * Yc.z; accm[11] += p3 * Yc.w;
      accm[12] += p3 * Yd.x; accm[13] += p3 * Yd.y; accm[14] += p3 * Yd.z;
      accm[15] += p3 * Yd.w;
    }
  }
  if (cur_r >= 0) {
    float* base = agg + ((size_t)cur_r << 10) + lane;
#pragma unroll
    for (int m = 0; m < 16; m++) atomicAdd(base + (m << 6), accm[m]);
  }
}

// ---------------------------------------------------------------- fused MFMA + agg, pass 2
__global__ __launch_bounds__(256) void k_fagg2(const _Float16* __restrict__ hid,
                                               const _Float16* __restrict__ bt,
                                               const float* __restrict__ Ysort,
                                               const float* __restrict__ up1,
                                               const int* __restrict__ ssort,
                                               const int* __restrict__ rsort,
                                               float* __restrict__ agg,
                                               int E, int EPAD) {
  __shared__ _Float16 __attribute__((aligned(16))) lds[4][16 * 384];  // 48 KB
  int wave = threadIdx.x >> 6, lane = threadIdx.x & 63;
  int q = lane >> 4, mr = lane & 15;
  _Float16* L = lds[wave];
  int j0 = (blockIdx.x * 4 + wave) * 16;
  if (j0 >= EPAD) return;

  // stage 1
  const half8* Ap = (const half8*)(hid + (size_t)(j0 + mr) * 64 + q * 8);
  half8 a0 = Ap[0];
  half8 a1 = Ap[4];
  const _Float16* bp = bt + (size_t)mr * 64 + q * 8;
#pragma unroll
  for (int T = 0; T < 24; T++) {
    half8 b0 = *(const half8*)(bp + T * 1024);
    half8 b1 = *(const half8*)(bp + T * 1024 + 32);
    f32x4 acc = {0.f, 0.f, 0.f, 0.f};
    acc = __builtin_amdgcn_mfma_f32_16x16x32_f16(a0, b0, acc, 0, 0, 0);
    acc = __builtin_amdgcn_mfma_f32_16x16x32_f16(a1, b1, acc, 0, 0, 0);
#pragma unroll
    for (int r = 0; r < 4; r++)
      L[(q * 4 + r) * 384 + T * 16 + mr] = (_Float16)acc[r];
  }

  // stage 2
  float accm[16];
#pragma unroll
  for (int m = 0; m < 16; m++) accm[m] = 0.0f;
  int cur_r = (j0 < E) ? rsort[j0] : -1;

  for (int t = 0; t < 16; t++) {
    int j = j0 + t;
    bool ok = (j < E);
    int rr = ok ? rsort[j] : -2;
    if (rr != cur_r) {
      if (cur_r >= 0) {
        float* base = agg + ((size_t)cur_r << 10) + lane;
#pragma unroll
        for (int m = 0; m < 16; m++) atomicAdd(base + (m << 6), accm[m]);
      }
#pragma unroll
      for (int m = 0; m < 16; m++) accm[m] = 0.0f;
      cur_r = rr;
    }
    if (ok) {
      int s = ssort[j];
      const float* hp = up1 + ((size_t)s << 8) + lane;
      float hs0 = hp[0], hs1 = hp[64], hs2 = hp[128], hs3 = hp[192];
      const _Float16* Rr = L + t * 384 + lane * 6;
      float R0 = (float)Rr[0], R1v = (float)Rr[1];
      float R2v = (float)Rr[2], R3v = (float)Rr[3];
      float c5 = (float)Rr[4], c9 = (float)Rr[5];
      float q0 = R0 * hs0, q1 = R1v * hs0, q2 = R2v * hs0, q3 = R3v * hs0;
      const float* Yj = Ysort + (size_t)j * 16;   // wave-uniform address
      float4 Ya = *(const float4*)(Yj);
      float4 Yb = *(const float4*)(Yj + 4);
      float4 Yc = *(const float4*)(Yj + 8);
      float4 Yd = *(const float4*)(Yj + 12);
      accm[0] += q0 + c9 * (hs1 * Ya.y + hs2 * Ya.z + hs3 * Ya.w);
      accm[1] += q1 * Ya.y + c5 * hs1;
      accm[2] += q1 * Ya.z + c5 * hs2;
      accm[3] += q1 * Ya.w + c5 * hs3;
      accm[4] += q2 * Yb.x;  accm[5] += q2 * Yb.y;  accm[6] += q2 * Yb.z;
      accm[7] += q2 * Yb.w;  accm[8] += q2 * Yc.x;
      accm[9]  += q3 * Yc.y; accm[10] += q3 * Yc.z; accm[11] += q3 * Yc.w;
      accm[12] += q3 * Yd.x; accm[13] += q3 * Yd.y; accm[14] += q3 * Yd.z;
      accm[15] += q3 * Yd.w;
    }
  }
  if (cur_r >= 0) {
    float* base = agg + ((size_t)cur_r << 10) + lane;
#pragma unroll
    for (int m = 0; m < 16; m++) atomicAdd(base + (m << 6), accm[m]);
  }
}

// ---------------------------------------------------------------- node kernel 1
// l-grouped weight reuse: m's sharing l reuse one W row load.
__global__ __launch_bounds__(64) void k_node1(float* __restrict__ agg0,
                                              const float* __restrict__ ld0,
                                              const float* __restrict__ sel_w,
                                              const float* __restrict__ pw0,
                                              const float* __restrict__ res_w,
                                              const float* __restrict__ lu1,
                                              const float* __restrict__ read0,
                                              const int* __restrict__ species,
                                              float* __restrict__ out,
                                              float* __restrict__ res,
                                              float* __restrict__ up1, int N) {
  int n = blockIdx.x, d = threadIdx.x;
  int sp = species[n];
  __shared__ float sA[1024], sB[1024];

  float* ag = agg0 + ((size_t)n << 10);
#pragma unroll
  for (int m = 0; m < 16; m++) {
    sA[m * 64 + d] = ag[m * 64 + d] * 0.0625f;
    ag[m * 64 + d] = 0.0f;     // re-zero for fagg2 (replaces memset)
  }
  __syncthreads();

  // fint[d][m] = sum_c agg[m][c] * ld0[l(m)][c][d]
  float fr[16];
#pragma unroll
  for (int m = 0; m < 16; m++) fr[m] = 0.0f;
#pragma unroll
  for (int l = 0; l < 4; l++) {
    int m0 = l * l, m1 = (l + 1) * (l + 1);
    const float* W = ld0 + l * 4096 + d;
#pragma unroll 8
    for (int c = 0; c < 64; c++) {
      float w = W[c * 64];
      for (int m = m0; m < m1; m++) fr[m] += sA[m * 64 + c] * w;
    }
  }
#pragma unroll
  for (int m = 0; m < 16; m++) sB[m * 64 + d] = fr[m];
  __syncthreads();

  // f[d][m] = sum_c fint[c][m] * sel_w[sp][l(m)][c][d]
  float f2r[16];
#pragma unroll
  for (int m = 0; m < 16; m++) f2r[m] = 0.0f;
#pragma unroll
  for (int l = 0; l < 4; l++) {
    int m0 = l * l, m1 = (l + 1) * (l + 1);
    const float* W = sel_w + ((size_t)(sp * 4 + l) << 12) + d;
#pragma unroll 8
    for (int c = 0; c < 64; c++) {
      float w = W[c * 64];
      for (int m = m0; m < m1; m++) f2r[m] += sB[m * 64 + c] * w;
    }
  }
  float s0 = f2r[0];
  float tt = 1.0f + s0 + s0 * s0;
#pragma unroll
  for (int m = 0; m < 4; m++) sA[m * 64 + d] = f2r[m] * tt;
  __syncthreads();

  // f1[d][m] = sum_c tf[c][m] * prod_w0[sp][c][d], m<4
  float f1r[4] = {0.f, 0.f, 0.f, 0.f};
  {
    const float* W = pw0 + ((size_t)sp << 12) + d;
#pragma unroll 8
    for (int c = 0; c < 64; c++) {
      float w = W[c * 64];
#pragma unroll
      for (int m = 0; m < 4; m++) f1r[m] += sA[m * 64 + c] * w;
    }
  }
#pragma unroll
  for (int m = 0; m < 4; m++) sB[m * 64 + d] = f1r[m];
  __syncthreads();

  float v = reduce64(f1r[0] * read0[d]);
  if (d == 0) out[2 * n] = v;

  // res[d] = sum_c f1[c][0] * res_w[sp][c][d] ; up1[0][d] via lu1[0]
  {
    const float* Wr = res_w + ((size_t)sp << 12) + d;
    const float* Wu = lu1 + d;
    float a = 0.0f, b = 0.0f;
#pragma unroll 8
    for (int c = 0; c < 64; c++) {
      float fv = sB[c];
      a += fv * Wr[c * 64];
      b += fv * Wu[c * 64];
    }
    res[(size_t)n * 64 + d] = a;
    up1[((size_t)n << 8) + d] = b;
  }
  // up1[m][d] via lu1[1], m=1..3 (shared weight row)
  {
    const float* Wu = lu1 + 4096 + d;
    float a1 = 0.f, a2 = 0.f, a3 = 0.f;
#pragma unroll 8
    for (int c = 0; c < 64; c++) {
      float w = Wu[c * 64];
      a1 += sB[64 + c] * w;
      a2 += sB[128 + c] * w;
      a3 += sB[192 + c] * w;
    }
    up1[((size_t)n << 8) + 64 + d] = a1;
    up1[((size_t)n << 8) + 128 + d] = a2;
    up1[((size_t)n << 8) + 192 + d] = a3;
  }
}

// ---------------------------------------------------------------- node kernel 2
__global__ __launch_bounds__(64) void k_node2(const float* __restrict__ agg1,
                                              const float* __restrict__ ld1,
                                              const float* __restrict__ pw1,
                                              const float* __restrict__ res,
                                              const float* __restrict__ mlp_w1,
                                              const float* __restrict__ mlp_w2,
                                              const int* __restrict__ species,
                                              float* __restrict__ out, int N) {
  int n = blockIdx.x, d = threadIdx.x;
  int sp = species[n];
  __shared__ float sA[1024];

  const float* ag = agg1 + ((size_t)n << 10);
#pragma unroll
  for (int m = 0; m < 16; m++) sA[m * 64 + d] = ag[m * 64 + d] * 0.0625f;
  __syncthreads();

  float g[16];
#pragma unroll
  for (int m = 0; m < 16; m++) g[m] = 0.0f;
#pragma unroll
  for (int l = 0; l < 4; l++) {
    int m0 = l * l, m1 = (l + 1) * (l + 1);
    const float* W = ld1 + l * 4096 + d;
#pragma unroll 8
    for (int c = 0; c < 64; c++) {
      float w = W[c * 64];
      for (int m = m0; m < m1; m++) g[m] += sA[m * 64 + c] * w;
    }
  }
  float inv = g[0];
#pragma unroll
  for (int m = 1; m < 16; m++) inv += g[m] * g[m];
  float qv = inv + inv * inv;
  __syncthreads();
  sA[d] = qv;
  __syncthreads();

  float a = res[(size_t)n * 64 + d];
  {
    const float* W = pw1 + ((size_t)sp << 12) + d;
#pragma unroll 8
    for (int c = 0; c < 64; c++) a += sA[c] * W[c * 64];
  }
  sA[64 + d] = a;
  __syncthreads();

  float val = 0.0f;
  if (d < 32) {
    float h = 0.0f;
#pragma unroll 8
    for (int c = 0; c < 64; c++) h += sA[64 + c] * mlp_w1[c * 32 + d];
    val = silu_f(h) * mlp_w2[d];
  }
  val = reduce64(val);
  if (d == 0) out[2 * n + 1] = val;
}

// ---------------------------------------------------------------- launch
extern "C" void kernel_launch(void* const* d_in, const int* in_sizes, int n_in,
                              void* d_out, int out_size, void* d_ws, size_t ws_size,
                              hipStream_t stream) {
  const float* ev      = (const float*)d_in[0];
  const float* embed   = (const float*)d_in[1];
  const float* rw1     = (const float*)d_in[2];
  const float* rw2     = (const float*)d_in[3];
  const float* lu0     = (const float*)d_in[4];
  const float* lu1     = (const float*)d_in[5];
  const float* ld      = (const float*)d_in[6];
  const float* sel_w   = (const float*)d_in[7];
  const float* pw0     = (const float*)d_in[8];
  const float* pw1     = (const float*)d_in[9];
  const float* res_w   = (const float*)d_in[10];
  const float* read0   = (const float*)d_in[11];
  const float* mlp_w1  = (const float*)d_in[12];
  const float* mlp_w2  = (const float*)d_in[13];
  const int* species   = (const int*)d_in[14];
  const int* senders   = (const int*)d_in[15];
  const int* receivers = (const int*)d_in[16];
  float* out = (float*)d_out;

  int N = in_sizes[14];
  int E = in_sizes[15];
  int EPAD = ((E + 63) / 64) * 64;   // 16 edges/wave x 4 waves/block

  float* ws = (float*)d_ws;
  size_t o = 0;
  float* agg  = ws + o;  o += (size_t)N * 1024;   // shared by both interactions
  float* up0  = ws + o;  o += (size_t)N * 64;
  float* up1  = ws + o;  o += (size_t)N * 256;
  float* resb = ws + o;  o += (size_t)N * 64;
  _Float16* b1t  = (_Float16*)(ws + o); o += 8192;          // 256x64 f16
  _Float16* b2t  = (_Float16*)(ws + o); o += 12288;         // 384x64 f16
  _Float16* hid0 = (_Float16*)(ws + o); o += (size_t)EPAD * 32;
  _Float16* hid1 = (_Float16*)(ws + o); o += (size_t)EPAD * 32;
  float* Ysort = ws + o; o += (size_t)EPAD * 16;
  int* row_start = (int*)(ws + o); o += (size_t)N + 1;
  int* cursor    = (int*)(ws + o); o += (size_t)N;
  int* perm      = (int*)(ws + o); o += (size_t)E;
  int* rsort     = (int*)(ws + o); o += (size_t)E;
  int* ssort     = (int*)(ws + o); o += (size_t)E;

  hipMemsetAsync(agg, 0, (size_t)N * 1024 * sizeof(float), stream);
  hipMemsetAsync(cursor, 0, (size_t)N * sizeof(int), stream);

  // CSR build (shared by both interactions)
  k_hist<<<(E + 255) / 256, 256, 0, stream>>>(receivers, cursor, E);
  k_scan<<<1, 256, 0, stream>>>(cursor, row_start, cursor, N);
  k_scatter<<<(E + 255) / 256, 256, 0, stream>>>(receivers, senders, cursor,
                                                 perm, rsort, ssort, E);

  k_pack<<<160, 256, 0, stream>>>(rw2, b1t, b2t);
  k_up0<<<(N + 3) / 4, 256, 0, stream>>>(embed, lu0, species, up0, N);
  k_geom<<<EPAD / 4, 256, 0, stream>>>(ev, rw1, perm, hid0, hid1, Ysort, E, EPAD);

  int fblocks = EPAD / 64;   // 4 waves x 16 edges per block
  k_fagg1<<<fblocks, 256, 0, stream>>>(hid0, b1t, Ysort, up0, ssort, rsort, agg, E, EPAD);
  k_node1<<<N, 64, 0, stream>>>(agg, ld, sel_w, pw0, res_w, lu1, read0, species,
                                out, resb, up1, N);
  k_fagg2<<<fblocks, 256, 0, stream>>>(hid1, b2t, Ysort, up1, ssort, rsort, agg, E, EPAD);
  k_node2<<<N, 64, 0, stream>>>(agg, ld + 16384, pw1, resb, mlp_w1, mlp_w2, species, out, N);
}

// Round 5
// 500.026 us; speedup vs baseline: 3.1680x; 1.1571x over previous
//
#include <hip/hip_runtime.h>
#include <math.h>

// MACE-like block. CSR-sorted edges + f16 MFMA R-GEMM fused with aggregation.
// R5: batch-prefetched gathers (scalar edge metadata via readfirstlane,
//     all hs gathers issued before MFMA stage), up1 in [n][c][4] layout for
//     dwordx4 gathers.
// N=10000 nodes, E=160000 edges, C=64, 16 sph, S=10 species.

typedef _Float16 half8 __attribute__((ext_vector_type(8)));
typedef float f32x4 __attribute__((ext_vector_type(4)));

__device__ __forceinline__ float silu_f(float x) { return x / (1.0f + expf(-x)); }

__device__ __forceinline__ float reduce64(float v) {
#pragma unroll
  for (int off = 32; off > 0; off >>= 1) v += __shfl_xor(v, off, 64);
  return v;
}

__device__ __forceinline__ void compute_Y(float x, float y, float z, float* Y) {
  float x2 = x * x, y2 = y * y, z2 = z * z;
  Y[0] = 1.0f;
  Y[1] = 1.7320508f * x;
  Y[2] = 1.7320508f * y;
  Y[3] = 1.7320508f * z;
  Y[4] = 3.8729833f * x * y;
  Y[5] = 3.8729833f * y * z;
  Y[6] = 1.118034f * (3.0f * z2 - 1.0f);
  Y[7] = 3.8729833f * x * z;
  Y[8] = 1.9364917f * (x2 - y2);
  Y[9] = 2.09165f * y * (3.0f * x2 - y2);
  Y[10] = 10.246951f * x * y * z;
  Y[11] = 1.6201852f * y * (5.0f * z2 - 1.0f);
  Y[12] = 1.3228757f * z * (5.0f * z2 - 3.0f);
  Y[13] = 1.6201852f * x * (5.0f * z2 - 1.0f);
  Y[14] = 5.1234753f * z * (x2 - y2);
  Y[15] = 2.09165f * x * (x2 - 3.0f * y2);
}

__device__ __forceinline__ void compute_rb(float r, float inv_r, float* rb) {
  float t = fminf(r * 0.2f, 1.0f);
  float t2 = t * t;
  float t5 = t2 * t2 * t;
  float env = 1.0f + t5 * (-21.0f + t * (35.0f - 15.0f * t));
  float th = 0.62831853f * r;  // pi*r/5
  float s1 = sinf(th), c1 = cosf(th);
  float c2 = 2.0f * c1;
  float sprev = 0.0f, scur = s1;
  float coef = 0.63245553f * inv_r * env;
#pragma unroll
  for (int k = 0; k < 8; k++) {
    rb[k] = coef * scur;
    float snxt = c2 * scur - sprev;
    sprev = scur; scur = snxt;
  }
}

// ---------------------------------------------------------------- CSR build
__global__ __launch_bounds__(256) void k_hist(const int* __restrict__ receivers,
                                              int* __restrict__ cnt, int E) {
  int e = blockIdx.x * 256 + threadIdx.x;
  if (e < E) atomicAdd(&cnt[receivers[e]], 1);
}

__global__ __launch_bounds__(256) void k_scan(const int* __restrict__ deg,
                                              int* __restrict__ row_start,
                                              int* __restrict__ cursor, int N) {
  __shared__ int part[256];
  int t = threadIdx.x;
  int K = (N + 255) / 256;
  int lo = t * K, hi = min(lo + K, N);
  int s = 0;
  for (int i = lo; i < hi; i++) s += deg[i];
  part[t] = s;
  __syncthreads();
  for (int d = 1; d < 256; d <<= 1) {
    int v = (t >= d) ? part[t - d] : 0;
    __syncthreads();
    part[t] += v;
    __syncthreads();
  }
  int run = (t == 0) ? 0 : part[t - 1];
  for (int i = lo; i < hi; i++) {
    int di = deg[i];            // deg aliases cursor; read before overwrite
    row_start[i] = run;
    cursor[i] = run;
    run += di;
  }
  if (t == 255) row_start[N] = part[255];
}

__global__ __launch_bounds__(256) void k_scatter(const int* __restrict__ receivers,
                                                 const int* __restrict__ senders,
                                                 int* __restrict__ cursor,
                                                 int* __restrict__ perm,
                                                 int* __restrict__ rsort,
                                                 int* __restrict__ ssort, int E) {
  int e = blockIdx.x * 256 + threadIdx.x;
  if (e < E) {
    int r = receivers[e];
    int pos = atomicAdd(&cursor[r], 1);
    perm[pos] = e;
    rsort[pos] = r;
    ssort[pos] = senders[e];
  }
}

// ---------------------------------------------------------------- pack rw2 -> f16 B^T
__global__ __launch_bounds__(256) void k_pack(const float* __restrict__ rw2,
                                              _Float16* __restrict__ b1t,
                                              _Float16* __restrict__ b2t) {
  int idx = blockIdx.x * 256 + threadIdx.x;
  if (idx < 16384) {
    int n = idx >> 6, k = idx & 63;
    int c = n >> 2, j = n & 3;
    b1t[idx] = (_Float16)rw2[k * 768 + c * 12 + j];
  } else if (idx < 40960) {
    int i2 = idx - 16384;
    int n = i2 >> 6, k = i2 & 63;
    int c = n / 6, j = n - c * 6;
    int col = (j < 4) ? j : ((j == 4) ? 5 : 9);
    b2t[i2] = (_Float16)rw2[49152 + k * 768 + c * 12 + col];
  }
}

// ---------------------------------------------------------------- up0
__global__ __launch_bounds__(256) void k_up0(const float* __restrict__ embed,
                                             const float* __restrict__ lu0,
                                             const int* __restrict__ species,
                                             float* __restrict__ up0, int N) {
  int wave = threadIdx.x >> 6, lane = threadIdx.x & 63;
  int n = (blockIdx.x << 2) + wave;
  if (n >= N) return;
  int sp = species[n];
  const float* er = embed + sp * 64;
  float acc = 0.0f;
#pragma unroll 8
  for (int c = 0; c < 64; c++) acc += er[c] * lu0[c * 64 + lane];
  up0[(size_t)n * 64 + lane] = acc;
}

// ---------------------------------------------------------------- geometry (sorted order)
__global__ __launch_bounds__(256) void k_geom(const float* __restrict__ ev,
                                              const float* __restrict__ rw1,
                                              const int* __restrict__ perm,
                                              _Float16* __restrict__ hid0,
                                              _Float16* __restrict__ hid1,
                                              float* __restrict__ Ysort,
                                              int* __restrict__ rsort,
                                              int* __restrict__ ssort,
                                              int E, int EPAD) {
  int wave = threadIdx.x >> 6, lane = threadIdx.x & 63;
  int j = blockIdx.x * 4 + wave;
  if (j >= EPAD) return;
  if (j >= E) {
    hid0[(size_t)j * 64 + lane] = (_Float16)0.0f;
    hid1[(size_t)j * 64 + lane] = (_Float16)0.0f;
    if (lane == 0) { rsort[j] = -1; ssort[j] = 0; }
    if (lane < 16) Ysort[(size_t)j * 16 + lane] = 0.0f;
    return;
  }
  int e = perm[j];
  float vx = ev[e * 3 + 0], vy = ev[e * 3 + 1], vz = ev[e * 3 + 2];
  float r = sqrtf(vx * vx + vy * vy + vz * vz);
  float inv_r = 1.0f / (r + 1e-8f);
  float Y[16]; compute_Y(vx * inv_r, vy * inv_r, vz * inv_r, Y);
  float rb[8]; compute_rb(r, inv_r, rb);

  float h0 = 0.0f, h1 = 0.0f;
#pragma unroll
  for (int k = 0; k < 8; k++) {
    h0 += rb[k] * rw1[k * 64 + lane];
    h1 += rb[k] * rw1[512 + k * 64 + lane];
  }
  hid0[(size_t)j * 64 + lane] = (_Float16)silu_f(h0);
  hid1[(size_t)j * 64 + lane] = (_Float16)silu_f(h1);

  // lane m (m<16) stores Y[m]; select without dynamic index (avoid scratch)
  float yv = Y[0];
#pragma unroll
  for (int m = 1; m < 16; m++) yv = (lane == m) ? Y[m] : yv;
  if (lane < 16) Ysort[(size_t)j * 16 + lane] = yv;
}

// ---------------------------------------------------------------- fused MFMA + agg, pass 1
// Per wave: 16 sorted edges. Scalar metadata loads -> batch hs gather prefetch
// -> MFMA R[16][256] into LDS (overlapping gather latency) -> per-edge message
// accumulation in regs, atomic flush on receiver change.
__global__ __launch_bounds__(256) void k_fagg1(const _Float16* __restrict__ hid,
                                               const _Float16* __restrict__ bt,
                                               const float* __restrict__ Ysort,
                                               const float* __restrict__ up0,
                                               const int* __restrict__ ssort,
                                               const int* __restrict__ rsort,
                                               float* __restrict__ agg, int E) {
  __shared__ _Float16 __attribute__((aligned(16))) lds[4][16 * 256];  // 32 KB
  int wave = threadIdx.x >> 6, lane = threadIdx.x & 63;
  int q = lane >> 4, mr = lane & 15;
  _Float16* L = lds[wave];
  int j0 = __builtin_amdgcn_readfirstlane((blockIdx.x * 4 + wave) * 16);

  // edge metadata: wave-uniform addresses -> scalar loads
  int rs[16], ss[16];
#pragma unroll
  for (int t = 0; t < 16; t++) {
    rs[t] = rsort[j0 + t];
    ss[t] = ssort[j0 + t];
  }
  // batch gather prefetch (independent, issued back-to-back)
  float hsv[16];
#pragma unroll
  for (int t = 0; t < 16; t++)
    hsv[t] = up0[((size_t)ss[t] << 6) + lane];

  // stage 1 (overlaps gather latency)
  const half8* Ap = (const half8*)(hid + (size_t)(j0 + mr) * 64 + q * 8);
  half8 a0 = Ap[0];
  half8 a1 = Ap[4];  // +32 halves
  const _Float16* bp = bt + (size_t)mr * 64 + q * 8;
#pragma unroll
  for (int T = 0; T < 16; T++) {
    half8 b0 = *(const half8*)(bp + T * 1024);
    half8 b1 = *(const half8*)(bp + T * 1024 + 32);
    f32x4 acc = {0.f, 0.f, 0.f, 0.f};
    acc = __builtin_amdgcn_mfma_f32_16x16x32_f16(a0, b0, acc, 0, 0, 0);
    acc = __builtin_amdgcn_mfma_f32_16x16x32_f16(a1, b1, acc, 0, 0, 0);
#pragma unroll
    for (int r = 0; r < 4; r++)
      L[(q * 4 + r) * 256 + T * 16 + mr] = (_Float16)acc[r];
  }

  // stage 2
  float accm[16];
#pragma unroll
  for (int m = 0; m < 16; m++) accm[m] = 0.0f;
  int cur_r = (j0 < E) ? rs[0] : -1;

#pragma unroll
  for (int t = 0; t < 16; t++) {
    int j = j0 + t;
    bool ok = (j < E);
    int rr = ok ? rs[t] : -2;
    if (rr != cur_r) {         // wave-uniform
      if (cur_r >= 0) {
        float* base = agg + ((size_t)cur_r << 10) + lane;
#pragma unroll
        for (int m = 0; m < 16; m++) atomicAdd(base + (m << 6), accm[m]);
      }
#pragma unroll
      for (int m = 0; m < 16; m++) accm[m] = 0.0f;
      cur_r = rr;
    }
    if (ok) {
      float hs0 = hsv[t];
      const _Float16* Rr = L + t * 256 + lane * 4;
      float p0 = (float)Rr[0] * hs0, p1 = (float)Rr[1] * hs0;
      float p2 = (float)Rr[2] * hs0, p3 = (float)Rr[3] * hs0;
      const float* Yj = Ysort + (size_t)j * 16;   // wave-uniform address
      float4 Ya = *(const float4*)(Yj);
      float4 Yb = *(const float4*)(Yj + 4);
      float4 Yc = *(const float4*)(Yj + 8);
      float4 Yd = *(const float4*)(Yj + 12);
      accm[0] += p0;
      accm[1] += p1 * Ya.y;  accm[2] += p1 * Ya.z;  accm[3] += p1 * Ya.w;
      accm[4] += p2 * Yb.x;  accm[5] += p2 * Yb.y;  accm[6] += p2 * Yb.z;
      accm[7] += p2 * Yb.w;  accm[8] += p2 * Yc.x;
      accm[9]  += p3 * Yc.y; accm[10] += p3 * Yc.z; accm[11] += p3 * Yc.w;
      accm[12] += p3 * Yd.x; accm[13] += p3 * Yd.y; accm[14] += p3 * Yd.z;
      accm[15] += p3 * Yd.w;
    }
  }
  if (cur_r >= 0) {
    float* base = agg + ((size_t)cur_r << 10) + lane;
#pragma unroll
    for (int m = 0; m < 16; m++) atomicAdd(base + (m << 6), accm[m]);
  }
}

// ---------------------------------------------------------------- fused MFMA + agg, pass 2
// up1 layout is [n][c][4] -> one dwordx4 gather per edge per lane.
__global__ __launch_bounds__(256) void k_fagg2(const _Float16* __restrict__ hid,
                                               const _Float16* __restrict__ bt,
                                               const float* __restrict__ Ysort,
                                               const float* __restrict__ up1,
                                               const int* __restrict__ ssort,
                                               const int* __restrict__ rsort,
                                               float* __restrict__ agg, int E) {
  __shared__ _Float16 __attribute__((aligned(16))) lds[4][16 * 384];  // 48 KB
  int wave = threadIdx.x >> 6, lane = threadIdx.x & 63;
  int q = lane >> 4, mr = lane & 15;
  _Float16* L = lds[wave];
  int j0 = __builtin_amdgcn_readfirstlane((blockIdx.x * 4 + wave) * 16);

  int rs[16], ss[16];
#pragma unroll
  for (int t = 0; t < 16; t++) {
    rs[t] = rsort[j0 + t];
    ss[t] = ssort[j0 + t];
  }
  // batch gather prefetch, first half
  float4 hA[8];
#pragma unroll
  for (int t = 0; t < 8; t++)
    hA[t] = *(const float4*)(up1 + ((size_t)ss[t] << 8) + lane * 4);

  // stage 1 (overlaps gather latency)
  const half8* Ap = (const half8*)(hid + (size_t)(j0 + mr) * 64 + q * 8);
  half8 a0 = Ap[0];
  half8 a1 = Ap[4];
  const _Float16* bp = bt + (size_t)mr * 64 + q * 8;
#pragma unroll
  for (int T = 0; T < 24; T++) {
    half8 b0 = *(const half8*)(bp + T * 1024);
    half8 b1 = *(const half8*)(bp + T * 1024 + 32);
    f32x4 acc = {0.f, 0.f, 0.f, 0.f};
    acc = __builtin_amdgcn_mfma_f32_16x16x32_f16(a0, b0, acc, 0, 0, 0);
    acc = __builtin_amdgcn_mfma_f32_16x16x32_f16(a1, b1, acc, 0, 0, 0);
#pragma unroll
    for (int r = 0; r < 4; r++)
      L[(q * 4 + r) * 384 + T * 16 + mr] = (_Float16)acc[r];
  }

  // second half of gathers (overlaps first-half stage-2 compute)
  float4 hB[8];
#pragma unroll
  for (int t = 0; t < 8; t++)
    hB[t] = *(const float4*)(up1 + ((size_t)ss[8 + t] << 8) + lane * 4);

  // stage 2
  float accm[16];
#pragma unroll
  for (int m = 0; m < 16; m++) accm[m] = 0.0f;
  int cur_r = (j0 < E) ? rs[0] : -1;

#pragma unroll
  for (int t = 0; t < 16; t++) {
    int j = j0 + t;
    bool ok = (j < E);
    int rr = ok ? rs[t] : -2;
    if (rr != cur_r) {
      if (cur_r >= 0) {
        float* base = agg + ((size_t)cur_r << 10) + lane;
#pragma unroll
        for (int m = 0; m < 16; m++) atomicAdd(base + (m << 6), accm[m]);
      }
#pragma unroll
      for (int m = 0; m < 16; m++) accm[m] = 0.0f;
      cur_r = rr;
    }
    if (ok) {
      float4 hs = (t < 8) ? hA[t & 7] : hB[t & 7];
      float hs0 = hs.x, hs1 = hs.y, hs2 = hs.z, hs3 = hs.w;
      const _Float16* Rr = L + t * 384 + lane * 6;
      float R0 = (float)Rr[0], R1v = (float)Rr[1];
      float R2v = (float)Rr[2], R3v = (float)Rr[3];
      float c5 = (float)Rr[4], c9 = (float)Rr[5];
      float q0 = R0 * hs0, q1 = R1v * hs0, q2 = R2v * hs0, q3 = R3v * hs0;
      const float* Yj = Ysort + (size_t)j * 16;
      float4 Ya = *(const float4*)(Yj);
      float4 Yb = *(const float4*)(Yj + 4);
      float4 Yc = *(const float4*)(Yj + 8);
      float4 Yd = *(const float4*)(Yj + 12);
      accm[0] += q0 + c9 * (hs1 * Ya.y + hs2 * Ya.z + hs3 * Ya.w);
      accm[1] += q1 * Ya.y + c5 * hs1;
      accm[2] += q1 * Ya.z + c5 * hs2;
      accm[3] += q1 * Ya.w + c5 * hs3;
      accm[4] += q2 * Yb.x;  accm[5] += q2 * Yb.y;  accm[6] += q2 * Yb.z;
      accm[7] += q2 * Yb.w;  accm[8] += q2 * Yc.x;
      accm[9]  += q3 * Yc.y; accm[10] += q3 * Yc.z; accm[11] += q3 * Yc.w;
      accm[12] += q3 * Yd.x; accm[13] += q3 * Yd.y; accm[14] += q3 * Yd.z;
      accm[15] += q3 * Yd.w;
    }
  }
  if (cur_r >= 0) {
    float* base = agg + ((size_t)cur_r << 10) + lane;
#pragma unroll
    for (int m = 0; m < 16; m++) atomicAdd(base + (m << 6), accm[m]);
  }
}

// ---------------------------------------------------------------- node kernel 1
__global__ __launch_bounds__(64) void k_node1(float* __restrict__ agg0,
                                              const float* __restrict__ ld0,
                                              const float* __restrict__ sel_w,
                                              const float* __restrict__ pw0,
                                              const float* __restrict__ res_w,
                                              const float* __restrict__ lu1,
                                              const float* __restrict__ read0,
                                              const int* __restrict__ species,
                                              float* __restrict__ out,
                                              float* __restrict__ res,
                                              float* __restrict__ up1, int N) {
  int n = blockIdx.x, d = threadIdx.x;
  int sp = species[n];
  __shared__ float sA[1024], sB[1024];

  float* ag = agg0 + ((size_t)n << 10);
#pragma unroll
  for (int m = 0; m < 16; m++) {
    sA[m * 64 + d] = ag[m * 64 + d] * 0.0625f;
    ag[m * 64 + d] = 0.0f;     // re-zero for fagg2 (replaces memset)
  }
  __syncthreads();

  float fr[16];
#pragma unroll
  for (int m = 0; m < 16; m++) fr[m] = 0.0f;
#pragma unroll
  for (int l = 0; l < 4; l++) {
    int m0 = l * l, m1 = (l + 1) * (l + 1);
    const float* W = ld0 + l * 4096 + d;
#pragma unroll 8
    for (int c = 0; c < 64; c++) {
      float w = W[c * 64];
      for (int m = m0; m < m1; m++) fr[m] += sA[m * 64 + c] * w;
    }
  }
#pragma unroll
  for (int m = 0; m < 16; m++) sB[m * 64 + d] = fr[m];
  __syncthreads();

  float f2r[16];
#pragma unroll
  for (int m = 0; m < 16; m++) f2r[m] = 0.0f;
#pragma unroll
  for (int l = 0; l < 4; l++) {
    int m0 = l * l, m1 = (l + 1) * (l + 1);
    const float* W = sel_w + ((size_t)(sp * 4 + l) << 12) + d;
#pragma unroll 8
    for (int c = 0; c < 64; c++) {
      float w = W[c * 64];
      for (int m = m0; m < m1; m++) f2r[m] += sB[m * 64 + c] * w;
    }
  }
  float s0 = f2r[0];
  float tt = 1.0f + s0 + s0 * s0;
#pragma unroll
  for (int m = 0; m < 4; m++) sA[m * 64 + d] = f2r[m] * tt;
  __syncthreads();

  float f1r[4] = {0.f, 0.f, 0.f, 0.f};
  {
    const float* W = pw0 + ((size_t)sp << 12) + d;
#pragma unroll 8
    for (int c = 0; c < 64; c++) {
      float w = W[c * 64];
#pragma unroll
      for (int m = 0; m < 4; m++) f1r[m] += sA[m * 64 + c] * w;
    }
  }
#pragma unroll
  for (int m = 0; m < 4; m++) sB[m * 64 + d] = f1r[m];
  __syncthreads();

  float v = reduce64(f1r[0] * read0[d]);
  if (d == 0) out[2 * n] = v;

  // res = f1[:,0] @ res_w ; up1 row (layout [n][d][m]) via lu1
  float u0, u1v, u2v, u3v;
  {
    const float* Wr = res_w + ((size_t)sp << 12) + d;
    const float* Wu = lu1 + d;
    float a = 0.0f, b = 0.0f;
#pragma unroll 8
    for (int c = 0; c < 64; c++) {
      float fv = sB[c];
      a += fv * Wr[c * 64];
      b += fv * Wu[c * 64];
    }
    res[(size_t)n * 64 + d] = a;
    u0 = b;
  }
  {
    const float* Wu = lu1 + 4096 + d;
    float a1 = 0.f, a2 = 0.f, a3 = 0.f;
#pragma unroll 8
    for (int c = 0; c < 64; c++) {
      float w = Wu[c * 64];
      a1 += sB[64 + c] * w;
      a2 += sB[128 + c] * w;
      a3 += sB[192 + c] * w;
    }
    u1v = a1; u2v = a2; u3v = a3;
  }
  float4 uu = {u0, u1v, u2v, u3v};
  *(float4*)(up1 + ((size_t)n << 8) + d * 4) = uu;
}

// ---------------------------------------------------------------- node kernel 2
__global__ __launch_bounds__(64) void k_node2(const float* __restrict__ agg1,
                                              const float* __restrict__ ld1,
                                              const float* __restrict__ pw1,
                                              const float* __restrict__ res,
                                              const float* __restrict__ mlp_w1,
                                              const float* __restrict__ mlp_w2,
                                              const int* __restrict__ species,
                                              float* __restrict__ out, int N) {
  int n = blockIdx.x, d = threadIdx.x;
  int sp = species[n];
  __shared__ float sA[1024];

  const float* ag = agg1 + ((size_t)n << 10);
#pragma unroll
  for (int m = 0; m < 16; m++) sA[m * 64 + d] = ag[m * 64 + d] * 0.0625f;
  __syncthreads();

  float g[16];
#pragma unroll
  for (int m = 0; m < 16; m++) g[m] = 0.0f;
#pragma unroll
  for (int l = 0; l < 4; l++) {
    int m0 = l * l, m1 = (l + 1) * (l + 1);
    const float* W = ld1 + l * 4096 + d;
#pragma unroll 8
    for (int c = 0; c < 64; c++) {
      float w = W[c * 64];
      for (int m = m0; m < m1; m++) g[m] += sA[m * 64 + c] * w;
    }
  }
  float inv = g[0];
#pragma unroll
  for (int m = 1; m < 16; m++) inv += g[m] * g[m];
  float qv = inv + inv * inv;
  __syncthreads();
  sA[d] = qv;
  __syncthreads();

  float a = res[(size_t)n * 64 + d];
  {
    const float* W = pw1 + ((size_t)sp << 12) + d;
#pragma unroll 8
    for (int c = 0; c < 64; c++) a += sA[c] * W[c * 64];
  }
  sA[64 + d] = a;
  __syncthreads();

  float val = 0.0f;
  if (d < 32) {
    float h = 0.0f;
#pragma unroll 8
    for (int c = 0; c < 64; c++) h += sA[64 + c] * mlp_w1[c * 32 + d];
    val = silu_f(h) * mlp_w2[d];
  }
  val = reduce64(val);
  if (d == 0) out[2 * n + 1] = val;
}

// ---------------------------------------------------------------- launch
extern "C" void kernel_launch(void* const* d_in, const int* in_sizes, int n_in,
                              void* d_out, int out_size, void* d_ws, size_t ws_size,
                              hipStream_t stream) {
  const float* ev      = (const float*)d_in[0];
  const float* embed   = (const float*)d_in[1];
  const float* rw1     = (const float*)d_in[2];
  const float* rw2     = (const float*)d_in[3];
  const float* lu0     = (const float*)d_in[4];
  const float* lu1     = (const float*)d_in[5];
  const float* ld      = (const float*)d_in[6];
  const float* sel_w   = (const float*)d_in[7];
  const float* pw0     = (const float*)d_in[8];
  const float* pw1     = (const float*)d_in[9];
  const float* res_w   = (const float*)d_in[10];
  const float* read0   = (const float*)d_in[11];
  const float* mlp_w1  = (const float*)d_in[12];
  const float* mlp_w2  = (const float*)d_in[13];
  const int* species   = (const int*)d_in[14];
  const int* senders   = (const int*)d_in[15];
  const int* receivers = (const int*)d_in[16];
  float* out = (float*)d_out;

  int N = in_sizes[14];
  int E = in_sizes[15];
  int EPAD = ((E + 63) / 64) * 64;   // 16 edges/wave x 4 waves/block

  float* ws = (float*)d_ws;
  size_t o = 0;
  float* agg  = ws + o;  o += (size_t)N * 1024;   // shared by both interactions
  float* up0  = ws + o;  o += (size_t)N * 64;
  float* up1  = ws + o;  o += (size_t)N * 256;    // layout [n][c][4]
  float* resb = ws + o;  o += (size_t)N * 64;
  _Float16* b1t  = (_Float16*)(ws + o); o += 8192;          // 256x64 f16
  _Float16* b2t  = (_Float16*)(ws + o); o += 12288;         // 384x64 f16
  _Float16* hid0 = (_Float16*)(ws + o); o += (size_t)EPAD * 32;
  _Float16* hid1 = (_Float16*)(ws + o); o += (size_t)EPAD * 32;
  float* Ysort = ws + o; o += (size_t)EPAD * 16;
  int* row_start = (int*)(ws + o); o += (size_t)N + 1;
  int* cursor    = (int*)(ws + o); o += (size_t)N;
  int* perm      = (int*)(ws + o); o += (size_t)E;
  int* rsort     = (int*)(ws + o); o += (size_t)EPAD;
  int* ssort     = (int*)(ws + o); o += (size_t)EPAD;

  hipMemsetAsync(agg, 0, (size_t)N * 1024 * sizeof(float), stream);
  hipMemsetAsync(cursor, 0, (size_t)N * sizeof(int), stream);

  // CSR build (shared by both interactions)
  k_hist<<<(E + 255) / 256, 256, 0, stream>>>(receivers, cursor, E);
  k_scan<<<1, 256, 0, stream>>>(cursor, row_start, cursor, N);
  k_scatter<<<(E + 255) / 256, 256, 0, stream>>>(receivers, senders, cursor,
                                                 perm, rsort, ssort, E);

  k_pack<<<160, 256, 0, stream>>>(rw2, b1t, b2t);
  k_up0<<<(N + 3) / 4, 256, 0, stream>>>(embed, lu0, species, up0, N);
  k_geom<<<EPAD / 4, 256, 0, stream>>>(ev, rw1, perm, hid0, hid1, Ysort,
                                       rsort, ssort, E, EPAD);

  int fblocks = EPAD / 64;   // 4 waves x 16 edges per block
  k_fagg1<<<fblocks, 256, 0, stream>>>(hid0, b1t, Ysort, up0, ssort, rsort, agg, E);
  k_node1<<<N, 64, 0, stream>>>(agg, ld, sel_w, pw0, res_w, lu1, read0, species,
                                out, resb, up1, N);
  k_fagg2<<<fblocks, 256, 0, stream>>>(hid1, b2t, Ysort, up1, ssort, rsort, agg, E);
  k_node2<<<N, 64, 0, stream>>>(agg, ld + 16384, pw1, resb, mlp_w1, mlp_w2, species, out, N);
}